// Round 1
// baseline (1314.842 us; speedup 1.0000x reference)
//
#include <hip/hip_runtime.h>

#define EPS 1e-5f
constexpr int NT = 256;

// ---------------- degree / CSR construction ----------------

__global__ __launch_bounds__(NT) void count_kernel(const int* __restrict__ dst, int* __restrict__ deg, int E) {
    int e = blockIdx.x * NT + threadIdx.x;
    if (e < E) atomicAdd(&deg[dst[e]], 1);
}

__global__ __launch_bounds__(NT) void dis_kernel(const int* __restrict__ deg, float* __restrict__ dis, int N) {
    int n = blockIdx.x * NT + threadIdx.x;
    if (n < N) dis[n] = rsqrtf((float)deg[n] + 1.0f);
}

__global__ __launch_bounds__(NT) void scan1_kernel(const int* __restrict__ deg, int* __restrict__ bsum, int N) {
    __shared__ int l[NT];
    int n = blockIdx.x * NT + threadIdx.x;
    int v = (n < N) ? deg[n] : 0;
    l[threadIdx.x] = v; __syncthreads();
    for (int off = NT / 2; off > 0; off >>= 1) {
        if (threadIdx.x < off) l[threadIdx.x] += l[threadIdx.x + off];
        __syncthreads();
    }
    if (threadIdx.x == 0) bsum[blockIdx.x] = l[0];
}

__global__ __launch_bounds__(512) void scan2_kernel(const int* __restrict__ bsum, int* __restrict__ bscan, int NB) {
    __shared__ int l[512];
    int t = threadIdx.x;
    int v = (t < NB) ? bsum[t] : 0;
    l[t] = v; __syncthreads();
    for (int off = 1; off < 512; off <<= 1) {
        int u = (t >= off) ? l[t - off] : 0;
        __syncthreads();
        l[t] += u;
        __syncthreads();
    }
    if (t < NB) bscan[t] = l[t] - v;   // exclusive
}

__global__ __launch_bounds__(NT) void scan3_kernel(const int* __restrict__ deg, const int* __restrict__ bscan,
                                                   int* __restrict__ row_start, int N) {
    __shared__ int l[NT];
    int t = threadIdx.x;
    int n = blockIdx.x * NT + t;
    int v = (n < N) ? deg[n] : 0;
    l[t] = v; __syncthreads();
    for (int off = 1; off < NT; off <<= 1) {
        int u = (t >= off) ? l[t - off] : 0;
        __syncthreads();
        l[t] += u;
        __syncthreads();
    }
    if (n < N) row_start[n] = bscan[blockIdx.x] + l[t] - v;
}

__global__ __launch_bounds__(NT) void fill_kernel(const int* __restrict__ src, const int* __restrict__ dst,
                                                  const int* __restrict__ row_start, int* __restrict__ cursor,
                                                  int* __restrict__ csr, int E) {
    int e = blockIdx.x * NT + threadIdx.x;
    if (e < E) {
        int d = dst[e];
        int p = row_start[d] + atomicAdd(&cursor[d], 1);
        csr[p] = src[e];
    }
}

// ---------------- GEMM: out[row] = dis[row] * (norm(X)[row] @ W) ----------------
// NORM applies relu(v*a[k]+c[k]) to each input element on load (folded BN+ReLU).

template<int K, int F, bool NORM>
__global__ __launch_bounds__(NT) void gemm_kernel(const float* __restrict__ X, const float* __restrict__ W,
                                                  const float* __restrict__ dis, const float* __restrict__ an,
                                                  const float* __restrict__ cn, float* __restrict__ out, int N) {
    constexpr int KC = 32;
    constexpr int CT = F / 8;       // col-thread count
    constexpr int RT = NT / CT;     // row-thread count
    constexpr int RPT = 64 / RT;    // rows per thread
    constexpr int ASZ = NORM ? K : 1;
    __shared__ float Xs[64][KC + 1];
    __shared__ float Ws[KC][F];
    __shared__ float as_[ASZ];
    __shared__ float cs_[ASZ];

    int tid = threadIdx.x;
    if (NORM) {
        for (int i = tid; i < K; i += NT) { as_[i] = an[i]; cs_[i] = cn[i]; }
        __syncthreads();
    }
    int row0 = blockIdx.x * 64;
    int tc = tid % CT, tr = tid / CT;

    float acc[RPT][8];
    #pragma unroll
    for (int i = 0; i < RPT; i++)
        #pragma unroll
        for (int j = 0; j < 8; j++) acc[i][j] = 0.f;

    for (int k0 = 0; k0 < K; k0 += KC) {
        #pragma unroll
        for (int i = 0; i < (64 * KC) / NT; i++) {
            int idx = tid + i * NT;
            int r = idx / KC, kk = idx % KC;
            int row = row0 + r;
            float v = 0.f;
            if (row < N) v = X[(size_t)row * K + k0 + kk];
            if (NORM) v = fmaxf(v * as_[k0 + kk] + cs_[k0 + kk], 0.f);
            Xs[r][kk] = v;
        }
        #pragma unroll
        for (int i = 0; i < (KC * F) / NT; i++) {
            int idx = tid + i * NT;
            int kk = idx / F, f = idx % F;
            Ws[kk][f] = W[(size_t)(k0 + kk) * F + f];
        }
        __syncthreads();
        #pragma unroll
        for (int kk = 0; kk < KC; kk++) {
            float wv[8];
            #pragma unroll
            for (int j = 0; j < 8; j++) wv[j] = Ws[kk][tc * 8 + j];
            #pragma unroll
            for (int i = 0; i < RPT; i++) {
                float xv = Xs[tr + i * RT][kk];
                #pragma unroll
                for (int j = 0; j < 8; j++) acc[i][j] = fmaf(xv, wv[j], acc[i][j]);
            }
        }
        __syncthreads();
    }
    #pragma unroll
    for (int i = 0; i < RPT; i++) {
        int row = row0 + tr + i * RT;
        if (row < N) {
            float d = dis[row];
            #pragma unroll
            for (int j = 0; j < 8; j++) out[(size_t)row * F + tc * 8 + j] = d * acc[i][j];
        }
    }
}

// ---------------- aggregation: pre[n] = dis[n]*(hd[n] + sum_{src in N(n)} hd[src]) + b ----------------

template<int F, int LPN>
__global__ __launch_bounds__(NT) void agg_kernel(const float* __restrict__ hd, const int* __restrict__ csr,
                                                 const int* __restrict__ row_start, const int* __restrict__ deg,
                                                 const float* __restrict__ dis, const float* __restrict__ b,
                                                 float* __restrict__ pre, int N) {
    constexpr int VPL = F / LPN;   // values per lane (2 or 1)
    int gid = blockIdx.x * NT + threadIdx.x;
    int node = gid / LPN;
    int lane = gid % LPN;
    if (node >= N) return;
    int beg = row_start[node];
    int cnt = deg[node];
    if constexpr (VPL == 2) {
        const float2* hd2 = (const float2*)hd;
        float2 s0 = hd2[(size_t)node * (F / 2) + lane];
        float2 s1 = make_float2(0.f, 0.f);
        int i = 0;
        for (; i + 1 < cnt; i += 2) {
            int a = csr[beg + i], c = csr[beg + i + 1];
            float2 va = hd2[(size_t)a * (F / 2) + lane];
            float2 vb = hd2[(size_t)c * (F / 2) + lane];
            s0.x += va.x; s0.y += va.y;
            s1.x += vb.x; s1.y += vb.y;
        }
        if (i < cnt) {
            float2 va = hd2[(size_t)csr[beg + i] * (F / 2) + lane];
            s0.x += va.x; s0.y += va.y;
        }
        float d = dis[node];
        float2 bv = ((const float2*)b)[lane];
        float2 r;
        r.x = d * (s0.x + s1.x) + bv.x;
        r.y = d * (s0.y + s1.y) + bv.y;
        ((float2*)pre)[(size_t)node * (F / 2) + lane] = r;
    } else {
        float s0 = hd[(size_t)node * F + lane], s1 = 0.f;
        int i = 0;
        for (; i + 1 < cnt; i += 2) {
            int a = csr[beg + i], c = csr[beg + i + 1];
            s0 += hd[(size_t)a * F + lane];
            s1 += hd[(size_t)c * F + lane];
        }
        if (i < cnt) s0 += hd[(size_t)csr[beg + i] * F + lane];
        pre[(size_t)node * F + lane] = dis[node] * (s0 + s1) + b[lane];
    }
}

// ---------------- BN statistics ----------------

template<int F>
__global__ __launch_bounds__(NT) void stats_kernel(const float* __restrict__ pre, float* __restrict__ S1,
                                                   float* __restrict__ S2, int N) {
    constexpr int RPB = NT / F;
    int tid = threadIdx.x;
    int f = tid % F, r0 = tid / F;
    float s1 = 0.f, s2 = 0.f;
    for (int node = blockIdx.x * RPB + r0; node < N; node += gridDim.x * RPB) {
        float v = pre[(size_t)node * F + f];
        s1 += v; s2 += v * v;
    }
    __shared__ float l1[NT], l2[NT];
    l1[tid] = s1; l2[tid] = s2;
    __syncthreads();
    if (tid < F) {
        #pragma unroll
        for (int j = 1; j < RPB; j++) { s1 += l1[tid + j * F]; s2 += l2[tid + j * F]; }
        atomicAdd(&S1[tid], s1);
        atomicAdd(&S2[tid], s2);
    }
}

__global__ void params_kernel(const float* __restrict__ S1, const float* __restrict__ S2,
                              const float* __restrict__ g, const float* __restrict__ bt,
                              float* __restrict__ a, float* __restrict__ c, int N, int F) {
    int f = threadIdx.x;
    if (f < F) {
        float inv = 1.0f / (float)N;
        float mu = S1[f] * inv;
        float var = fmaxf(S2[f] * inv - mu * mu, 0.f);
        float av = g[f] * rsqrtf(var + EPS);
        a[f] = av;
        c[f] = bt[f] - mu * av;
    }
}

// ---------------- final FC: out[n] = relu(bn3(pre3[n])) @ Wfc + bfc ----------------

__global__ __launch_bounds__(NT) void fc_kernel(const float* __restrict__ pre, const float* __restrict__ a,
                                                const float* __restrict__ c, const float* __restrict__ wfc,
                                                const float* __restrict__ bfc, float* __restrict__ out, int N) {
    __shared__ float wa[32], wc[32], ww[32];
    int tid = threadIdx.x;
    if (tid < 32) { wa[tid] = a[tid]; wc[tid] = c[tid]; ww[tid] = wfc[tid]; }
    __syncthreads();
    int n = blockIdx.x * NT + tid;
    if (n >= N) return;
    const float4* p = (const float4*)(pre + (size_t)n * 32);
    float acc = bfc[0];
    #pragma unroll
    for (int i = 0; i < 8; i++) {
        float4 v = p[i];
        float vv[4] = {v.x, v.y, v.z, v.w};
        #pragma unroll
        for (int j = 0; j < 4; j++) {
            int f = i * 4 + j;
            float u = fmaxf(vv[j] * wa[f] + wc[f], 0.f);
            acc += u * ww[f];
        }
    }
    out[n] = acc;
}

// ---------------- launch ----------------

extern "C" void kernel_launch(void* const* d_in, const int* in_sizes, int n_in,
                              void* d_out, int out_size, void* d_ws, size_t ws_size,
                              hipStream_t stream) {
    const float* x   = (const float*)d_in[0];
    const int*   ei  = (const int*)d_in[1];
    const float* W1  = (const float*)d_in[2];
    const float* b1  = (const float*)d_in[3];
    const float* g1  = (const float*)d_in[4];
    const float* bt1 = (const float*)d_in[5];
    const float* W2  = (const float*)d_in[6];
    const float* b2  = (const float*)d_in[7];
    const float* g2  = (const float*)d_in[8];
    const float* bt2 = (const float*)d_in[9];
    const float* W3  = (const float*)d_in[10];
    const float* b3  = (const float*)d_in[11];
    const float* g3  = (const float*)d_in[12];
    const float* bt3 = (const float*)d_in[13];
    const float* Wfc = (const float*)d_in[14];
    const float* bfc = (const float*)d_in[15];
    float* out = (float*)d_out;

    int N = in_sizes[0] / 256;
    int E = in_sizes[1] / 2;
    const int* src = ei;
    const int* dst = ei + E;

    char* ws = (char*)d_ws;
    size_t off = 0;
    auto alloc = [&](size_t bytes) -> char* {
        char* p = ws + off;
        off += (bytes + 255) & ~(size_t)255;
        return p;
    };
    float* bufA      = (float*)alloc((size_t)N * 128 * 4);   // hd (dis-scaled GEMM output)
    float* bufB      = (float*)alloc((size_t)N * 128 * 4);   // pre-BN aggregated
    int*   csr       = (int*)alloc((size_t)E * 4);
    int*   deg       = (int*)alloc((size_t)N * 4);
    int*   row_start = (int*)alloc((size_t)N * 4);
    int*   cursor    = (int*)alloc((size_t)N * 4);
    float* dis       = (float*)alloc((size_t)N * 4);
    int NB = (N + NT - 1) / NT;
    int* bsum  = (int*)alloc((size_t)NB * 4);
    int* bscan = (int*)alloc((size_t)NB * 4);
    float* stats = (float*)alloc(448 * 4 * 2);
    float* S1_1 = stats;       float* S2_1 = S1_1 + 128;
    float* S1_2 = S2_1 + 128;  float* S2_2 = S1_2 + 64;
    float* S1_3 = S2_2 + 64;   float* S2_3 = S1_3 + 32;
    float* a1 = S2_3 + 32; float* c1 = a1 + 128;
    float* a2 = c1 + 128;  float* c2 = a2 + 64;
    float* a3 = c2 + 64;   float* c3 = a3 + 32;

    hipMemsetAsync(deg, 0, (size_t)N * 4, stream);
    hipMemsetAsync(cursor, 0, (size_t)N * 4, stream);
    hipMemsetAsync(stats, 0, 448 * 4, stream);

    int EB = (E + NT - 1) / NT;
    count_kernel<<<EB, NT, 0, stream>>>(dst, deg, E);
    dis_kernel<<<NB, NT, 0, stream>>>(deg, dis, N);
    scan1_kernel<<<NB, NT, 0, stream>>>(deg, bsum, N);
    scan2_kernel<<<1, 512, 0, stream>>>(bsum, bscan, NB);
    scan3_kernel<<<NB, NT, 0, stream>>>(deg, bscan, row_start, N);
    fill_kernel<<<EB, NT, 0, stream>>>(src, dst, row_start, cursor, csr, E);

    int GB = (N + 63) / 64;
    // layer 1
    gemm_kernel<256, 128, false><<<GB, NT, 0, stream>>>(x, W1, dis, nullptr, nullptr, bufA, N);
    agg_kernel<128, 64><<<(N * 64 + NT - 1) / NT, NT, 0, stream>>>(bufA, csr, row_start, deg, dis, b1, bufB, N);
    stats_kernel<128><<<256, NT, 0, stream>>>(bufB, S1_1, S2_1, N);
    params_kernel<<<1, 128, 0, stream>>>(S1_1, S2_1, g1, bt1, a1, c1, N, 128);
    // layer 2
    gemm_kernel<128, 64, true><<<GB, NT, 0, stream>>>(bufB, W2, dis, a1, c1, bufA, N);
    agg_kernel<64, 64><<<(N * 64 + NT - 1) / NT, NT, 0, stream>>>(bufA, csr, row_start, deg, dis, b2, bufB, N);
    stats_kernel<64><<<256, NT, 0, stream>>>(bufB, S1_2, S2_2, N);
    params_kernel<<<1, 64, 0, stream>>>(S1_2, S2_2, g2, bt2, a2, c2, N, 64);
    // layer 3
    gemm_kernel<64, 32, true><<<GB, NT, 0, stream>>>(bufB, W3, dis, a2, c2, bufA, N);
    agg_kernel<32, 32><<<(N * 32 + NT - 1) / NT, NT, 0, stream>>>(bufA, csr, row_start, deg, dis, b3, bufB, N);
    stats_kernel<32><<<256, NT, 0, stream>>>(bufB, S1_3, S2_3, N);
    params_kernel<<<1, 32, 0, stream>>>(S1_3, S2_3, g3, bt3, a3, c3, N, 32);
    // head
    fc_kernel<<<NB, NT, 0, stream>>>(bufB, a3, c3, Wfc, bfc, out, N);
}

// Round 2
// 1123.259 us; speedup vs baseline: 1.1706x; 1.1706x over previous
//
#include <hip/hip_runtime.h>
#include <hip/hip_fp16.h>
#include <type_traits>

#define EPS 1e-5f
constexpr int NT = 256;

// ---------------- degree / CSR construction ----------------

__global__ __launch_bounds__(NT) void count_kernel(const int* __restrict__ dst, int* __restrict__ deg, int E) {
    int e = blockIdx.x * NT + threadIdx.x;
    if (e < E) atomicAdd(&deg[dst[e]], 1);
}

__global__ __launch_bounds__(NT) void dis_kernel(const int* __restrict__ deg, float* __restrict__ dis, int N) {
    int n = blockIdx.x * NT + threadIdx.x;
    if (n < N) dis[n] = rsqrtf((float)deg[n] + 1.0f);
}

__global__ __launch_bounds__(NT) void scan1_kernel(const int* __restrict__ deg, int* __restrict__ bsum, int N) {
    __shared__ int l[NT];
    int n = blockIdx.x * NT + threadIdx.x;
    int v = (n < N) ? deg[n] : 0;
    l[threadIdx.x] = v; __syncthreads();
    for (int off = NT / 2; off > 0; off >>= 1) {
        if (threadIdx.x < off) l[threadIdx.x] += l[threadIdx.x + off];
        __syncthreads();
    }
    if (threadIdx.x == 0) bsum[blockIdx.x] = l[0];
}

__global__ __launch_bounds__(512) void scan2_kernel(const int* __restrict__ bsum, int* __restrict__ bscan, int NB) {
    __shared__ int l[512];
    int t = threadIdx.x;
    int v = (t < NB) ? bsum[t] : 0;
    l[t] = v; __syncthreads();
    for (int off = 1; off < 512; off <<= 1) {
        int u = (t >= off) ? l[t - off] : 0;
        __syncthreads();
        l[t] += u;
        __syncthreads();
    }
    if (t < NB) bscan[t] = l[t] - v;   // exclusive
}

__global__ __launch_bounds__(NT) void scan3_kernel(const int* __restrict__ deg, const int* __restrict__ bscan,
                                                   int* __restrict__ row_start, int N) {
    __shared__ int l[NT];
    int t = threadIdx.x;
    int n = blockIdx.x * NT + t;
    int v = (n < N) ? deg[n] : 0;
    l[t] = v; __syncthreads();
    for (int off = 1; off < NT; off <<= 1) {
        int u = (t >= off) ? l[t - off] : 0;
        __syncthreads();
        l[t] += u;
        __syncthreads();
    }
    if (n < N) row_start[n] = bscan[blockIdx.x] + l[t] - v;
}

__global__ __launch_bounds__(NT) void fill_kernel(const int* __restrict__ src, const int* __restrict__ dst,
                                                  const int* __restrict__ row_start, int* __restrict__ cursor,
                                                  int* __restrict__ csr, int E) {
    int e = blockIdx.x * NT + threadIdx.x;
    if (e < E) {
        int d = dst[e];
        int p = row_start[d] + atomicAdd(&cursor[d], 1);
        csr[p] = src[e];
    }
}

// ---------------- GEMM: out[row] = fp16( dis[row] * (norm(X)[row] @ W) ) ----------------
// NORM: input is fp16 pre-BN; applies relu(v*a[k]+c[k]) on load (folded BN+ReLU).

template<int K, int F, bool NORM>
__global__ __launch_bounds__(NT) void gemm_kernel(const void* __restrict__ Xv, const float* __restrict__ W,
                                                  const float* __restrict__ dis, const float* __restrict__ an,
                                                  const float* __restrict__ cn, __half* __restrict__ out, int N) {
    using XT = typename std::conditional<NORM, __half, float>::type;
    const XT* __restrict__ X = (const XT*)Xv;
    constexpr int KC = 32;
    constexpr int CT = F / 8;       // col-thread count
    constexpr int RT = NT / CT;     // row-thread count
    constexpr int RPT = 64 / RT;    // rows per thread
    constexpr int ASZ = NORM ? K : 1;
    __shared__ float Xs[64][KC + 1];
    __shared__ float Ws[KC][F];
    __shared__ float as_[ASZ];
    __shared__ float cs_[ASZ];

    int tid = threadIdx.x;
    if (NORM) {
        for (int i = tid; i < K; i += NT) { as_[i] = an[i]; cs_[i] = cn[i]; }
        __syncthreads();
    }
    int row0 = blockIdx.x * 64;
    int tc = tid % CT, tr = tid / CT;

    float acc[RPT][8];
    #pragma unroll
    for (int i = 0; i < RPT; i++)
        #pragma unroll
        for (int j = 0; j < 8; j++) acc[i][j] = 0.f;

    for (int k0 = 0; k0 < K; k0 += KC) {
        #pragma unroll
        for (int i = 0; i < (64 * KC) / NT; i++) {
            int idx = tid + i * NT;
            int r = idx / KC, kk = idx % KC;
            int row = row0 + r;
            float v = 0.f;
            if (row < N) {
                if constexpr (NORM) v = __half2float(X[(size_t)row * K + k0 + kk]);
                else                v = ((const float*)X)[(size_t)row * K + k0 + kk];
            }
            if (NORM) v = fmaxf(v * as_[k0 + kk] + cs_[k0 + kk], 0.f);
            Xs[r][kk] = v;
        }
        #pragma unroll
        for (int i = 0; i < (KC * F) / NT; i++) {
            int idx = tid + i * NT;
            int kk = idx / F, f = idx % F;
            Ws[kk][f] = W[(size_t)(k0 + kk) * F + f];
        }
        __syncthreads();
        #pragma unroll
        for (int kk = 0; kk < KC; kk++) {
            float wv[8];
            #pragma unroll
            for (int j = 0; j < 8; j++) wv[j] = Ws[kk][tc * 8 + j];
            #pragma unroll
            for (int i = 0; i < RPT; i++) {
                float xv = Xs[tr + i * RT][kk];
                #pragma unroll
                for (int j = 0; j < 8; j++) acc[i][j] = fmaf(xv, wv[j], acc[i][j]);
            }
        }
        __syncthreads();
    }
    #pragma unroll
    for (int i = 0; i < RPT; i++) {
        int row = row0 + tr + i * RT;
        if (row < N) {
            float d = dis[row];
            __half2* op = (__half2*)out + (size_t)row * (F / 2) + tc * 4;
            #pragma unroll
            for (int j = 0; j < 4; j++)
                op[j] = __floats2half2_rn(d * acc[i][2 * j], d * acc[i][2 * j + 1]);
        }
    }
}

// ---------------- aggregation: pre[n] = fp16( dis[n]*(hd[n] + sum_{src} hd[src]) + b ) ----------------
// One wave per node. H = F/2 half2 slots; EPI = 64/H edges processed per wave-iteration.

template<int F, int U>
__global__ __launch_bounds__(NT) void agg_kernel(const __half* __restrict__ hd, const int* __restrict__ csr,
                                                 const int* __restrict__ row_start, const int* __restrict__ deg,
                                                 const float* __restrict__ dis, const float* __restrict__ b,
                                                 __half* __restrict__ pre, int N) {
    constexpr int H = F / 2;
    constexpr int EPI = 64 / H;
    int wid = (blockIdx.x * NT + threadIdx.x) >> 6;
    int lane = threadIdx.x & 63;
    int fpos = lane % H;
    int sub = lane / H;
    if (wid >= N) return;
    int node = wid;
    int beg = row_start[node];
    int cnt = deg[node];
    const __half2* __restrict__ hd2 = (const __half2*)hd;

    float sx[U], sy[U];
    #pragma unroll
    for (int u = 0; u < U; u++) { sx[u] = 0.f; sy[u] = 0.f; }
    if (sub == 0) {
        float2 f = __half22float2(hd2[(size_t)node * H + fpos]);
        sx[0] = f.x; sy[0] = f.y;
    }
    int i = 0;
    for (; i + EPI * U <= cnt; i += EPI * U) {
        int srcs[U];
        #pragma unroll
        for (int u = 0; u < U; u++) srcs[u] = csr[beg + i + u * EPI + sub];
        #pragma unroll
        for (int u = 0; u < U; u++) {
            float2 f = __half22float2(hd2[(size_t)srcs[u] * H + fpos]);
            sx[u] += f.x; sy[u] += f.y;
        }
    }
    for (; i + sub < cnt; i += EPI) {
        int s = csr[beg + i + sub];
        float2 f = __half22float2(hd2[(size_t)s * H + fpos]);
        sx[0] += f.x; sy[0] += f.y;
    }
    #pragma unroll
    for (int u = 1; u < U; u++) { sx[0] += sx[u]; sy[0] += sy[u]; }
    #pragma unroll
    for (int m = H; m < 64; m <<= 1) {
        sx[0] += __shfl_xor(sx[0], m, 64);
        sy[0] += __shfl_xor(sy[0], m, 64);
    }
    if (sub == 0) {
        float d = dis[node];
        float2 bv = ((const float2*)b)[fpos];
        ((__half2*)pre)[(size_t)node * H + fpos] =
            __floats2half2_rn(d * sx[0] + bv.x, d * sy[0] + bv.y);
    }
}

// ---------------- BN statistics ----------------

template<int F>
__global__ __launch_bounds__(NT) void stats_kernel(const __half* __restrict__ pre, float* __restrict__ S1,
                                                   float* __restrict__ S2, int N) {
    constexpr int RPB = NT / F;
    int tid = threadIdx.x;
    int f = tid % F, r0 = tid / F;
    float s1 = 0.f, s2 = 0.f;
    for (int node = blockIdx.x * RPB + r0; node < N; node += gridDim.x * RPB) {
        float v = __half2float(pre[(size_t)node * F + f]);
        s1 += v; s2 += v * v;
    }
    __shared__ float l1[NT], l2[NT];
    l1[tid] = s1; l2[tid] = s2;
    __syncthreads();
    if (tid < F) {
        #pragma unroll
        for (int j = 1; j < RPB; j++) { s1 += l1[tid + j * F]; s2 += l2[tid + j * F]; }
        atomicAdd(&S1[tid], s1);
        atomicAdd(&S2[tid], s2);
    }
}

__global__ void params_kernel(const float* __restrict__ S1, const float* __restrict__ S2,
                              const float* __restrict__ g, const float* __restrict__ bt,
                              float* __restrict__ a, float* __restrict__ c, int N, int F) {
    int f = threadIdx.x;
    if (f < F) {
        float inv = 1.0f / (float)N;
        float mu = S1[f] * inv;
        float var = fmaxf(S2[f] * inv - mu * mu, 0.f);
        float av = g[f] * rsqrtf(var + EPS);
        a[f] = av;
        c[f] = bt[f] - mu * av;
    }
}

// ---------------- final FC: out[n] = relu(bn3(pre3[n])) @ Wfc + bfc ----------------

__global__ __launch_bounds__(NT) void fc_kernel(const __half* __restrict__ pre, const float* __restrict__ a,
                                                const float* __restrict__ c, const float* __restrict__ wfc,
                                                const float* __restrict__ bfc, float* __restrict__ out, int N) {
    __shared__ float wa[32], wc[32], ww[32];
    int tid = threadIdx.x;
    if (tid < 32) { wa[tid] = a[tid]; wc[tid] = c[tid]; ww[tid] = wfc[tid]; }
    __syncthreads();
    int n = blockIdx.x * NT + tid;
    if (n >= N) return;
    const __half2* p = (const __half2*)(pre + (size_t)n * 32);
    float acc = bfc[0];
    #pragma unroll
    for (int i = 0; i < 16; i++) {
        float2 v = __half22float2(p[i]);
        int f = i * 2;
        acc += fmaxf(v.x * wa[f] + wc[f], 0.f) * ww[f];
        acc += fmaxf(v.y * wa[f + 1] + wc[f + 1], 0.f) * ww[f + 1];
    }
    out[n] = acc;
}

// ---------------- launch ----------------

extern "C" void kernel_launch(void* const* d_in, const int* in_sizes, int n_in,
                              void* d_out, int out_size, void* d_ws, size_t ws_size,
                              hipStream_t stream) {
    const float* x   = (const float*)d_in[0];
    const int*   ei  = (const int*)d_in[1];
    const float* W1  = (const float*)d_in[2];
    const float* b1  = (const float*)d_in[3];
    const float* g1  = (const float*)d_in[4];
    const float* bt1 = (const float*)d_in[5];
    const float* W2  = (const float*)d_in[6];
    const float* b2  = (const float*)d_in[7];
    const float* g2  = (const float*)d_in[8];
    const float* bt2 = (const float*)d_in[9];
    const float* W3  = (const float*)d_in[10];
    const float* b3  = (const float*)d_in[11];
    const float* g3  = (const float*)d_in[12];
    const float* bt3 = (const float*)d_in[13];
    const float* Wfc = (const float*)d_in[14];
    const float* bfc = (const float*)d_in[15];
    float* out = (float*)d_out;

    int N = in_sizes[0] / 256;
    int E = in_sizes[1] / 2;
    const int* src = ei;
    const int* dst = ei + E;

    char* ws = (char*)d_ws;
    size_t off = 0;
    auto alloc = [&](size_t bytes) -> char* {
        char* p = ws + off;
        off += (bytes + 255) & ~(size_t)255;
        return p;
    };
    __half* bufA     = (__half*)alloc((size_t)N * 128 * 2);   // hd (dis-scaled GEMM output, fp16)
    __half* bufB     = (__half*)alloc((size_t)N * 128 * 2);   // pre-BN aggregated (fp16)
    int*   csr       = (int*)alloc((size_t)E * 4);
    int*   deg       = (int*)alloc((size_t)N * 4);
    int*   row_start = (int*)alloc((size_t)N * 4);
    int*   cursor    = (int*)alloc((size_t)N * 4);
    float* dis       = (float*)alloc((size_t)N * 4);
    int NB = (N + NT - 1) / NT;
    int* bsum  = (int*)alloc((size_t)NB * 4);
    int* bscan = (int*)alloc((size_t)NB * 4);
    float* stats = (float*)alloc(448 * 4 * 2);
    float* S1_1 = stats;       float* S2_1 = S1_1 + 128;
    float* S1_2 = S2_1 + 128;  float* S2_2 = S1_2 + 64;
    float* S1_3 = S2_2 + 64;   float* S2_3 = S1_3 + 32;
    float* a1 = S2_3 + 32; float* c1 = a1 + 128;
    float* a2 = c1 + 128;  float* c2 = a2 + 64;
    float* a3 = c2 + 64;   float* c3 = a3 + 32;

    hipMemsetAsync(deg, 0, (size_t)N * 4, stream);
    hipMemsetAsync(cursor, 0, (size_t)N * 4, stream);
    hipMemsetAsync(stats, 0, 448 * 4, stream);

    int EB = (E + NT - 1) / NT;
    count_kernel<<<EB, NT, 0, stream>>>(dst, deg, E);
    dis_kernel<<<NB, NT, 0, stream>>>(deg, dis, N);
    scan1_kernel<<<NB, NT, 0, stream>>>(deg, bsum, N);
    scan2_kernel<<<1, 512, 0, stream>>>(bsum, bscan, NB);
    scan3_kernel<<<NB, NT, 0, stream>>>(deg, bscan, row_start, N);
    fill_kernel<<<EB, NT, 0, stream>>>(src, dst, row_start, cursor, csr, E);

    int GB = (N + 63) / 64;
    int AB = (N + 3) / 4;   // agg: one wave per node, 4 nodes per block
    // layer 1
    gemm_kernel<256, 128, false><<<GB, NT, 0, stream>>>(x, W1, dis, nullptr, nullptr, bufA, N);
    agg_kernel<128, 4><<<AB, NT, 0, stream>>>(bufA, csr, row_start, deg, dis, b1, bufB, N);
    stats_kernel<128><<<256, NT, 0, stream>>>(bufB, S1_1, S2_1, N);
    params_kernel<<<1, 128, 0, stream>>>(S1_1, S2_1, g1, bt1, a1, c1, N, 128);
    // layer 2
    gemm_kernel<128, 64, true><<<GB, NT, 0, stream>>>(bufB, W2, dis, a1, c1, bufA, N);
    agg_kernel<64, 4><<<AB, NT, 0, stream>>>(bufA, csr, row_start, deg, dis, b2, bufB, N);
    stats_kernel<64><<<256, NT, 0, stream>>>(bufB, S1_2, S2_2, N);
    params_kernel<<<1, 64, 0, stream>>>(S1_2, S2_2, g2, bt2, a2, c2, N, 64);
    // layer 3
    gemm_kernel<64, 32, true><<<GB, NT, 0, stream>>>(bufB, W3, dis, a2, c2, bufA, N);
    agg_kernel<32, 2><<<AB, NT, 0, stream>>>(bufA, csr, row_start, deg, dis, b3, bufB, N);
    stats_kernel<32><<<256, NT, 0, stream>>>(bufB, S1_3, S2_3, N);
    params_kernel<<<1, 32, 0, stream>>>(S1_3, S2_3, g3, bt3, a3, c3, N, 32);
    // head
    fc_kernel<<<NB, NT, 0, stream>>>(bufB, a3, c3, Wfc, bfc, out, N);
}

// Round 3
// 878.537 us; speedup vs baseline: 1.4966x; 1.2786x over previous
//
#include <hip/hip_runtime.h>
#include <hip/hip_fp16.h>

#define EPS 1e-5f
constexpr int NT = 256;

typedef _Float16 v8h __attribute__((ext_vector_type(8)));
typedef float v4f __attribute__((ext_vector_type(4)));

// ---------------- degree / CSR construction ----------------

__global__ __launch_bounds__(NT) void count_kernel(const int* __restrict__ dst, int* __restrict__ deg, int E) {
    int e = blockIdx.x * NT + threadIdx.x;
    if (e < E) atomicAdd(&deg[dst[e]], 1);
}

__global__ __launch_bounds__(NT) void dis_kernel(const int* __restrict__ deg, float* __restrict__ dis, int N) {
    int n = blockIdx.x * NT + threadIdx.x;
    if (n < N) dis[n] = rsqrtf((float)deg[n] + 1.0f);
}

__global__ __launch_bounds__(NT) void scan1_kernel(const int* __restrict__ deg, int* __restrict__ bsum, int N) {
    __shared__ int l[NT];
    int n = blockIdx.x * NT + threadIdx.x;
    int v = (n < N) ? deg[n] : 0;
    l[threadIdx.x] = v; __syncthreads();
    for (int off = NT / 2; off > 0; off >>= 1) {
        if (threadIdx.x < off) l[threadIdx.x] += l[threadIdx.x + off];
        __syncthreads();
    }
    if (threadIdx.x == 0) bsum[blockIdx.x] = l[0];
}

__global__ __launch_bounds__(512) void scan2_kernel(const int* __restrict__ bsum, int* __restrict__ bscan, int NB) {
    __shared__ int l[512];
    int t = threadIdx.x;
    int v = (t < NB) ? bsum[t] : 0;
    l[t] = v; __syncthreads();
    for (int off = 1; off < 512; off <<= 1) {
        int u = (t >= off) ? l[t - off] : 0;
        __syncthreads();
        l[t] += u;
        __syncthreads();
    }
    if (t < NB) bscan[t] = l[t] - v;   // exclusive
}

__global__ __launch_bounds__(NT) void scan3_kernel(const int* __restrict__ deg, const int* __restrict__ bscan,
                                                   int* __restrict__ row_start, int N) {
    __shared__ int l[NT];
    int t = threadIdx.x;
    int n = blockIdx.x * NT + t;
    int v = (n < N) ? deg[n] : 0;
    l[t] = v; __syncthreads();
    for (int off = 1; off < NT; off <<= 1) {
        int u = (t >= off) ? l[t - off] : 0;
        __syncthreads();
        l[t] += u;
        __syncthreads();
    }
    if (n < N) row_start[n] = bscan[blockIdx.x] + l[t] - v;
}

__global__ __launch_bounds__(NT) void fill_kernel(const int* __restrict__ src, const int* __restrict__ dst,
                                                  const int* __restrict__ row_start, int* __restrict__ cursor,
                                                  int* __restrict__ csr, int E) {
    int e = blockIdx.x * NT + threadIdx.x;
    if (e < E) {
        int d = dst[e];
        int p = row_start[d] + atomicAdd(&cursor[d], 1);
        csr[p] = src[e];
    }
}

// ---------------- weight prep: W fp32 [K][F] -> Wt fp16 [F][K] (transposed) ----------------

__global__ __launch_bounds__(NT) void prepw_kernel(const float* __restrict__ W1, const float* __restrict__ W2,
                                                   const float* __restrict__ W3, __half* __restrict__ Wt1,
                                                   __half* __restrict__ Wt2, __half* __restrict__ Wt3) {
    int i = blockIdx.x * NT + threadIdx.x;
    if (i < 256 * 128) {
        int k = i >> 7, f = i & 127;
        Wt1[f * 256 + k] = __float2half(W1[i]);
    } else if (i < 256 * 128 + 128 * 64) {
        int j = i - 256 * 128; int k = j >> 6, f = j & 63;
        Wt2[f * 128 + k] = __float2half(W2[j]);
    } else if (i < 256 * 128 + 128 * 64 + 64 * 32) {
        int j = i - 256 * 128 - 128 * 64; int k = j >> 5, f = j & 31;
        Wt3[f * 64 + k] = __float2half(W3[j]);
    }
}

// ---------------- MFMA GEMM: out[row] = fp16( dis[row] * (norm(X)[row] @ W) ) ----------------
// A frag: [m=lane&15][k=quad*8+j], B frag: [n=lane&15][k=quad*8+j] (Wt is B^T layout),
// C/D: col=lane&15, row=quad*4+reg  (verified m89/m92 layout).
// NORM: X is fp16; applies relu(v*a[k]+c[k]) on load (folded BN+ReLU).

template<int K, int F, bool NORM>
__global__ __launch_bounds__(NT) void mgemm_kernel(const void* __restrict__ Xv, const __half* __restrict__ Wt,
                                                   const float* __restrict__ dis, const float* __restrict__ an,
                                                   const float* __restrict__ cn, __half* __restrict__ out, int N) {
    constexpr int KC = 32;
    constexpr int CG = F / 16;      // 16-wide col groups
    constexpr int LDA = KC + 8;     // 40 halves: 80B row stride, keeps b128 16B-aligned, 2-way max conflict
    constexpr int ASZ = NORM ? K : 1;
    __shared__ __half As[64 * LDA];
    __shared__ __half Bs[F * LDA];
    __shared__ float as_[ASZ], cs_[ASZ];

    int tid = threadIdx.x;
    if constexpr (NORM) {
        for (int i = tid; i < K; i += NT) { as_[i] = an[i]; cs_[i] = cn[i]; }
        __syncthreads();
    }
    int row0 = blockIdx.x * 64;
    int wid = tid >> 6, lane = tid & 63;
    int quad = lane >> 4, l16 = lane & 15;
    int tr = tid >> 3;            // 0..31
    int tk = (tid & 7) * 4;       // 0..28

    v4f acc[CG];
    #pragma unroll
    for (int g = 0; g < CG; g++) acc[g] = (v4f)0.f;

    for (int k0 = 0; k0 < K; k0 += KC) {
        // stage A tile (64 rows x 32 k) as fp16
        #pragma unroll
        for (int r = tr; r < 64; r += 32) {
            int row = row0 + r;
            __half h0, h1, h2, h3;
            if (row < N) {
                if constexpr (NORM) {
                    const __half2* xp = (const __half2*)((const __half*)Xv + (size_t)row * K + k0 + tk);
                    float2 v0 = __half22float2(xp[0]);
                    float2 v1 = __half22float2(xp[1]);
                    h0 = __float2half(fmaxf(v0.x * as_[k0 + tk]     + cs_[k0 + tk],     0.f));
                    h1 = __float2half(fmaxf(v0.y * as_[k0 + tk + 1] + cs_[k0 + tk + 1], 0.f));
                    h2 = __float2half(fmaxf(v1.x * as_[k0 + tk + 2] + cs_[k0 + tk + 2], 0.f));
                    h3 = __float2half(fmaxf(v1.y * as_[k0 + tk + 3] + cs_[k0 + tk + 3], 0.f));
                } else {
                    float4 v = *(const float4*)((const float*)Xv + (size_t)row * K + k0 + tk);
                    h0 = __float2half(v.x); h1 = __float2half(v.y);
                    h2 = __float2half(v.z); h3 = __float2half(v.w);
                }
            } else {
                h0 = h1 = h2 = h3 = __float2half(0.f);
            }
            __half2* dst = (__half2*)&As[r * LDA + tk];
            dst[0] = __halves2half2(h0, h1);
            dst[1] = __halves2half2(h2, h3);
        }
        // stage B tile (F rows x 32 k) from Wt fp16
        #pragma unroll
        for (int n = tr; n < F; n += 32) {
            const __half2* wp = (const __half2*)(Wt + (size_t)n * K + k0 + tk);
            __half2* dst = (__half2*)&Bs[n * LDA + tk];
            dst[0] = wp[0];
            dst[1] = wp[1];
        }
        __syncthreads();
        v8h a = *(const v8h*)&As[(wid * 16 + l16) * LDA + quad * 8];
        #pragma unroll
        for (int g = 0; g < CG; g++) {
            v8h b = *(const v8h*)&Bs[(g * 16 + l16) * LDA + quad * 8];
            acc[g] = __builtin_amdgcn_mfma_f32_16x16x32_f16(a, b, acc[g], 0, 0, 0);
        }
        __syncthreads();
    }
    // epilogue: D row = quad*4+reg (within wave's 16-row stripe), col = l16
    #pragma unroll
    for (int reg = 0; reg < 4; reg++) {
        int row = row0 + wid * 16 + quad * 4 + reg;
        if (row < N) {
            float d = dis[row];
            #pragma unroll
            for (int g = 0; g < CG; g++)
                out[(size_t)row * F + g * 16 + l16] = __float2half(d * acc[g][reg]);
        }
    }
}

// ---------------- aggregation: pre[n] = fp16( dis[n]*(hd[n] + sum_{src} hd[src]) + b ) ----------------
// One wave per node. H = F/2 half2 slots; EPI = 64/H edges per wave-iteration.

template<int F, int U>
__global__ __launch_bounds__(NT) void agg_kernel(const __half* __restrict__ hd, const int* __restrict__ csr,
                                                 const int* __restrict__ row_start, const int* __restrict__ deg,
                                                 const float* __restrict__ dis, const float* __restrict__ b,
                                                 __half* __restrict__ pre, int N) {
    constexpr int H = F / 2;
    constexpr int EPI = 64 / H;
    int wid = (blockIdx.x * NT + threadIdx.x) >> 6;
    int lane = threadIdx.x & 63;
    int fpos = lane % H;
    int sub = lane / H;
    if (wid >= N) return;
    int node = wid;
    int beg = row_start[node];
    int cnt = deg[node];
    const __half2* __restrict__ hd2 = (const __half2*)hd;

    float sx[U], sy[U];
    #pragma unroll
    for (int u = 0; u < U; u++) { sx[u] = 0.f; sy[u] = 0.f; }
    if (sub == 0) {
        float2 f = __half22float2(hd2[(size_t)node * H + fpos]);
        sx[0] = f.x; sy[0] = f.y;
    }
    int i = 0;
    for (; i + EPI * U <= cnt; i += EPI * U) {
        int srcs[U];
        #pragma unroll
        for (int u = 0; u < U; u++) srcs[u] = csr[beg + i + u * EPI + sub];
        #pragma unroll
        for (int u = 0; u < U; u++) {
            float2 f = __half22float2(hd2[(size_t)srcs[u] * H + fpos]);
            sx[u] += f.x; sy[u] += f.y;
        }
    }
    for (; i + sub < cnt; i += EPI) {
        int s = csr[beg + i + sub];
        float2 f = __half22float2(hd2[(size_t)s * H + fpos]);
        sx[0] += f.x; sy[0] += f.y;
    }
    #pragma unroll
    for (int u = 1; u < U; u++) { sx[0] += sx[u]; sy[0] += sy[u]; }
    #pragma unroll
    for (int m = H; m < 64; m <<= 1) {
        sx[0] += __shfl_xor(sx[0], m, 64);
        sy[0] += __shfl_xor(sy[0], m, 64);
    }
    if (sub == 0) {
        float d = dis[node];
        float2 bv = ((const float2*)b)[fpos];
        ((__half2*)pre)[(size_t)node * H + fpos] =
            __floats2half2_rn(d * sx[0] + bv.x, d * sy[0] + bv.y);
    }
}

// ---------------- BN statistics ----------------

template<int F>
__global__ __launch_bounds__(NT) void stats_kernel(const __half* __restrict__ pre, float* __restrict__ S1,
                                                   float* __restrict__ S2, int N) {
    constexpr int RPB = NT / F;
    int tid = threadIdx.x;
    int f = tid % F, r0 = tid / F;
    float s1 = 0.f, s2 = 0.f;
    for (int node = blockIdx.x * RPB + r0; node < N; node += gridDim.x * RPB) {
        float v = __half2float(pre[(size_t)node * F + f]);
        s1 += v; s2 += v * v;
    }
    __shared__ float l1[NT], l2[NT];
    l1[tid] = s1; l2[tid] = s2;
    __syncthreads();
    if (tid < F) {
        #pragma unroll
        for (int j = 1; j < RPB; j++) { s1 += l1[tid + j * F]; s2 += l2[tid + j * F]; }
        atomicAdd(&S1[tid], s1);
        atomicAdd(&S2[tid], s2);
    }
}

__global__ void params_kernel(const float* __restrict__ S1, const float* __restrict__ S2,
                              const float* __restrict__ g, const float* __restrict__ bt,
                              float* __restrict__ a, float* __restrict__ c, int N, int F) {
    int f = threadIdx.x;
    if (f < F) {
        float inv = 1.0f / (float)N;
        float mu = S1[f] * inv;
        float var = fmaxf(S2[f] * inv - mu * mu, 0.f);
        float av = g[f] * rsqrtf(var + EPS);
        a[f] = av;
        c[f] = bt[f] - mu * av;
    }
}

// ---------------- final FC: out[n] = relu(bn3(pre3[n])) @ Wfc + bfc ----------------

__global__ __launch_bounds__(NT) void fc_kernel(const __half* __restrict__ pre, const float* __restrict__ a,
                                                const float* __restrict__ c, const float* __restrict__ wfc,
                                                const float* __restrict__ bfc, float* __restrict__ out, int N) {
    __shared__ float wa[32], wc[32], ww[32];
    int tid = threadIdx.x;
    if (tid < 32) { wa[tid] = a[tid]; wc[tid] = c[tid]; ww[tid] = wfc[tid]; }
    __syncthreads();
    int n = blockIdx.x * NT + tid;
    if (n >= N) return;
    const __half2* p = (const __half2*)(pre + (size_t)n * 32);
    float acc = bfc[0];
    #pragma unroll
    for (int i = 0; i < 16; i++) {
        float2 v = __half22float2(p[i]);
        int f = i * 2;
        acc += fmaxf(v.x * wa[f] + wc[f], 0.f) * ww[f];
        acc += fmaxf(v.y * wa[f + 1] + wc[f + 1], 0.f) * ww[f + 1];
    }
    out[n] = acc;
}

// ---------------- launch ----------------

extern "C" void kernel_launch(void* const* d_in, const int* in_sizes, int n_in,
                              void* d_out, int out_size, void* d_ws, size_t ws_size,
                              hipStream_t stream) {
    const float* x   = (const float*)d_in[0];
    const int*   ei  = (const int*)d_in[1];
    const float* W1  = (const float*)d_in[2];
    const float* b1  = (const float*)d_in[3];
    const float* g1  = (const float*)d_in[4];
    const float* bt1 = (const float*)d_in[5];
    const float* W2  = (const float*)d_in[6];
    const float* b2  = (const float*)d_in[7];
    const float* g2  = (const float*)d_in[8];
    const float* bt2 = (const float*)d_in[9];
    const float* W3  = (const float*)d_in[10];
    const float* b3  = (const float*)d_in[11];
    const float* g3  = (const float*)d_in[12];
    const float* bt3 = (const float*)d_in[13];
    const float* Wfc = (const float*)d_in[14];
    const float* bfc = (const float*)d_in[15];
    float* out = (float*)d_out;

    int N = in_sizes[0] / 256;
    int E = in_sizes[1] / 2;
    const int* src = ei;
    const int* dst = ei + E;

    char* ws = (char*)d_ws;
    size_t off = 0;
    auto alloc = [&](size_t bytes) -> char* {
        char* p = ws + off;
        off += (bytes + 255) & ~(size_t)255;
        return p;
    };
    __half* bufA     = (__half*)alloc((size_t)N * 128 * 2);   // hd (dis-scaled GEMM output, fp16)
    __half* bufB     = (__half*)alloc((size_t)N * 128 * 2);   // pre-BN aggregated (fp16)
    int*   csr       = (int*)alloc((size_t)E * 4);
    int*   deg       = (int*)alloc((size_t)N * 4);
    int*   row_start = (int*)alloc((size_t)N * 4);
    int*   cursor    = (int*)alloc((size_t)N * 4);
    float* dis       = (float*)alloc((size_t)N * 4);
    __half* Wt1      = (__half*)alloc(256 * 128 * 2);
    __half* Wt2      = (__half*)alloc(128 * 64 * 2);
    __half* Wt3      = (__half*)alloc(64 * 32 * 2);
    int NB = (N + NT - 1) / NT;
    int* bsum  = (int*)alloc((size_t)NB * 4);
    int* bscan = (int*)alloc((size_t)NB * 4);
    float* stats = (float*)alloc(448 * 4 * 2);
    float* S1_1 = stats;       float* S2_1 = S1_1 + 128;
    float* S1_2 = S2_1 + 128;  float* S2_2 = S1_2 + 64;
    float* S1_3 = S2_2 + 64;   float* S2_3 = S1_3 + 32;
    float* a1 = S2_3 + 32; float* c1 = a1 + 128;
    float* a2 = c1 + 128;  float* c2 = a2 + 64;
    float* a3 = c2 + 64;   float* c3 = a3 + 32;

    hipMemsetAsync(deg, 0, (size_t)N * 4, stream);
    hipMemsetAsync(cursor, 0, (size_t)N * 4, stream);
    hipMemsetAsync(stats, 0, 448 * 4, stream);

    int EB = (E + NT - 1) / NT;
    count_kernel<<<EB, NT, 0, stream>>>(dst, deg, E);
    dis_kernel<<<NB, NT, 0, stream>>>(deg, dis, N);
    scan1_kernel<<<NB, NT, 0, stream>>>(deg, bsum, N);
    scan2_kernel<<<1, 512, 0, stream>>>(bsum, bscan, NB);
    scan3_kernel<<<NB, NT, 0, stream>>>(deg, bscan, row_start, N);
    fill_kernel<<<EB, NT, 0, stream>>>(src, dst, row_start, cursor, csr, E);
    prepw_kernel<<<(256 * 128 + 128 * 64 + 64 * 32 + NT - 1) / NT, NT, 0, stream>>>(W1, W2, W3, Wt1, Wt2, Wt3);

    int GB = (N + 63) / 64;
    int AB = (N + 3) / 4;   // agg: one wave per node, 4 nodes per block
    // layer 1
    mgemm_kernel<256, 128, false><<<GB, NT, 0, stream>>>(x, Wt1, dis, nullptr, nullptr, bufA, N);
    agg_kernel<128, 4><<<AB, NT, 0, stream>>>(bufA, csr, row_start, deg, dis, b1, bufB, N);
    stats_kernel<128><<<256, NT, 0, stream>>>(bufB, S1_1, S2_1, N);
    params_kernel<<<1, 128, 0, stream>>>(S1_1, S2_1, g1, bt1, a1, c1, N, 128);
    // layer 2
    mgemm_kernel<128, 64, true><<<GB, NT, 0, stream>>>(bufB, Wt2, dis, a1, c1, bufA, N);
    agg_kernel<64, 4><<<AB, NT, 0, stream>>>(bufA, csr, row_start, deg, dis, b2, bufB, N);
    stats_kernel<64><<<256, NT, 0, stream>>>(bufB, S1_2, S2_2, N);
    params_kernel<<<1, 64, 0, stream>>>(S1_2, S2_2, g2, bt2, a2, c2, N, 64);
    // layer 3
    mgemm_kernel<64, 32, true><<<GB, NT, 0, stream>>>(bufB, Wt3, dis, a2, c2, bufA, N);
    agg_kernel<32, 2><<<AB, NT, 0, stream>>>(bufA, csr, row_start, deg, dis, b3, bufB, N);
    stats_kernel<32><<<256, NT, 0, stream>>>(bufB, S1_3, S2_3, N);
    params_kernel<<<1, 32, 0, stream>>>(S1_3, S2_3, g3, bt3, a3, c3, N, 32);
    // head
    fc_kernel<<<NB, NT, 0, stream>>>(bufB, a3, c3, Wfc, bfc, out, N);
}

// Round 4
// 683.548 us; speedup vs baseline: 1.9236x; 1.2853x over previous
//
#include <hip/hip_runtime.h>
#include <hip/hip_fp16.h>

#define EPS 1e-5f
constexpr int NT = 256;
constexpr int BSH = 9;            // bucket = dst >> 9 (512 nodes per bucket)
constexpr int BNODES = 1 << BSH;
constexpr int CH = 4096;          // edges per partition block

typedef _Float16 v8h __attribute__((ext_vector_type(8)));
typedef float v4f __attribute__((ext_vector_type(4)));

// ---------------- bucket histogram (LDS-staged) ----------------

__global__ __launch_bounds__(NT) void bhist_kernel(const int* __restrict__ dst, int* __restrict__ gbhist,
                                                   int E, int NBUK) {
    __shared__ int h[512];
    int tid = threadIdx.x;
    for (int i = tid; i < 512; i += NT) h[i] = 0;
    __syncthreads();
    for (int e = blockIdx.x * NT + tid; e < E; e += gridDim.x * NT)
        atomicAdd(&h[dst[e] >> BSH], 1);
    __syncthreads();
    for (int i = tid; i < NBUK; i += NT)
        if (h[i]) atomicAdd(&gbhist[i], h[i]);
}

// ---------------- bucket scan: bbase[0..NBUK] (exclusive), gcur = bbase ----------------

__global__ __launch_bounds__(NT) void bscan_kernel(const int* __restrict__ gbhist, int* __restrict__ bbase,
                                                   int* __restrict__ gcur, int E, int NBUK) {
    __shared__ int wsum[5];
    int tid = threadIdx.x;
    int lane = tid & 63, wid = tid >> 6;
    int e0 = (2 * tid < NBUK) ? gbhist[2 * tid] : 0;
    int e1 = (2 * tid + 1 < NBUK) ? gbhist[2 * tid + 1] : 0;
    int u = e0 + e1;
    int incl = u;
    #pragma unroll
    for (int off = 1; off < 64; off <<= 1) {
        int t = __shfl_up(incl, off, 64);
        if (lane >= off) incl += t;
    }
    if (lane == 63) wsum[wid] = incl;
    __syncthreads();
    if (tid == 0) { int s = 0; for (int w = 0; w < 4; w++) { int t = wsum[w]; wsum[w] = s; s += t; } }
    __syncthreads();
    int base = wsum[wid] + incl - u;
    if (2 * tid < NBUK)     { bbase[2 * tid] = base;          gcur[2 * tid] = base; }
    if (2 * tid + 1 < NBUK) { bbase[2 * tid + 1] = base + e0; gcur[2 * tid + 1] = base + e0; }
    if (tid == 0) bbase[NBUK] = E;
}

// ---------------- phase 1: partition edges into ebuf by bucket (block-local counting sort) ----------------

__global__ __launch_bounds__(NT) void part_kernel(const int* __restrict__ src, const int* __restrict__ dst,
                                                  int* __restrict__ gcur, int2* __restrict__ ebuf,
                                                  int E, int NBUK) {
    constexpr int EPT = CH / NT;   // 16 edges per thread
    __shared__ int hist[512];
    __shared__ int lscan[512];
    __shared__ int gbase[512];
    __shared__ int2 stage[CH];
    int tid = threadIdx.x;
    int lane = tid & 63;
    int e0 = blockIdx.x * CH;

    for (int i = tid; i < 512; i += NT) hist[i] = 0;
    __syncthreads();

    int2 ed[EPT]; int rank[EPT]; int buk[EPT];
    #pragma unroll
    for (int j = 0; j < EPT; j++) {
        int e = e0 + j * NT + tid;
        if (e < E) {
            ed[j].x = src[e]; ed[j].y = dst[e];
            buk[j] = ed[j].y >> BSH;
            rank[j] = atomicAdd(&hist[buk[j]], 1);
        } else buk[j] = -1;
    }
    __syncthreads();
    // exclusive scan of hist (<=512 entries) by wave 0: 8 buckets per lane
    if (tid < 64) {
        int bi = tid * 8;
        int v[8]; int s = 0;
        #pragma unroll
        for (int j = 0; j < 8; j++) { v[j] = s; s += hist[bi + j]; }
        int incl = s;
        #pragma unroll
        for (int off = 1; off < 64; off <<= 1) {
            int t = __shfl_up(incl, off, 64);
            if (lane >= off) incl += t;
        }
        int lb = incl - s;
        #pragma unroll
        for (int j = 0; j < 8; j++) lscan[bi + j] = lb + v[j];
    }
    __syncthreads();
    // reserve global ranges
    for (int i = tid; i < NBUK; i += NT) {
        int c = hist[i];
        gbase[i] = c ? atomicAdd(&gcur[i], c) : 0;
    }
    // scatter into LDS sorted order
    #pragma unroll
    for (int j = 0; j < EPT; j++)
        if (buk[j] >= 0) stage[lscan[buk[j]] + rank[j]] = ed[j];
    __syncthreads();
    // coalesced flush of contiguous bucket runs
    int cnt = min(E - e0, CH);
    for (int i = tid; i < cnt; i += NT) {
        int2 e = stage[i];
        int b = e.y >> BSH;
        ebuf[gbase[b] + (i - lscan[b])] = e;
    }
}

// ---------------- phase 2: per-bucket deg/row_start/dis + csr fill (L2-local scatter) ----------------

__global__ __launch_bounds__(NT) void bfill_kernel(const int2* __restrict__ ebuf, const int* __restrict__ bbase,
                                                   int* __restrict__ deg, int* __restrict__ row_start,
                                                   float* __restrict__ dis, int* __restrict__ csr, int N) {
    __shared__ int ldeg[BNODES];
    __shared__ int lrs[BNODES];
    __shared__ int wsum[5];
    int tid = threadIdx.x;
    int lane = tid & 63, wid = tid >> 6;
    int b = blockIdx.x;
    int node0 = b << BSH;
    int nn = min(BNODES, N - node0);
    int beg = bbase[b], end = bbase[b + 1];

    for (int i = tid; i < BNODES; i += NT) ldeg[i] = 0;
    __syncthreads();
    for (int i = beg + tid; i < end; i += NT)
        atomicAdd(&ldeg[ebuf[i].y - node0], 1);
    __syncthreads();
    // exclusive scan of ldeg[0..511]: 2 entries per thread
    int e0 = ldeg[2 * tid], e1 = ldeg[2 * tid + 1];
    int u = e0 + e1;
    int incl = u;
    #pragma unroll
    for (int off = 1; off < 64; off <<= 1) {
        int t = __shfl_up(incl, off, 64);
        if (lane >= off) incl += t;
    }
    if (lane == 63) wsum[wid] = incl;
    __syncthreads();
    if (tid == 0) { int s = 0; for (int w = 0; w < 4; w++) { int t = wsum[w]; wsum[w] = s; s += t; } }
    __syncthreads();
    int base = wsum[wid] + incl - u;
    lrs[2 * tid] = base;
    lrs[2 * tid + 1] = base + e0;
    __syncthreads();
    for (int i = tid; i < nn; i += NT) {
        int dg = ldeg[i];
        deg[node0 + i] = dg;
        row_start[node0 + i] = beg + lrs[i];
        dis[node0 + i] = rsqrtf((float)dg + 1.0f);
    }
    __syncthreads();
    for (int i = tid; i < BNODES; i += NT) ldeg[i] = 0;   // reuse as cursor
    __syncthreads();
    for (int i = beg + tid; i < end; i += NT) {
        int2 e = ebuf[i];
        int l = e.y - node0;
        int off = atomicAdd(&ldeg[l], 1);
        csr[beg + lrs[l] + off] = e.x;
    }
}

// ---------------- weight prep: W fp32 [K][F] -> Wt fp16 [F][K] (transposed) ----------------

__global__ __launch_bounds__(NT) void prepw_kernel(const float* __restrict__ W1, const float* __restrict__ W2,
                                                   const float* __restrict__ W3, __half* __restrict__ Wt1,
                                                   __half* __restrict__ Wt2, __half* __restrict__ Wt3) {
    int i = blockIdx.x * NT + threadIdx.x;
    if (i < 256 * 128) {
        int k = i >> 7, f = i & 127;
        Wt1[f * 256 + k] = __float2half(W1[i]);
    } else if (i < 256 * 128 + 128 * 64) {
        int j = i - 256 * 128; int k = j >> 6, f = j & 63;
        Wt2[f * 128 + k] = __float2half(W2[j]);
    } else if (i < 256 * 128 + 128 * 64 + 64 * 32) {
        int j = i - 256 * 128 - 128 * 64; int k = j >> 5, f = j & 31;
        Wt3[f * 64 + k] = __float2half(W3[j]);
    }
}

// ---------------- MFMA GEMM: out[row] = fp16( dis[row] * (norm(X)[row] @ W) ) ----------------

template<int K, int F, bool NORM>
__global__ __launch_bounds__(NT) void mgemm_kernel(const void* __restrict__ Xv, const __half* __restrict__ Wt,
                                                   const float* __restrict__ dis, const float* __restrict__ an,
                                                   const float* __restrict__ cn, __half* __restrict__ out, int N) {
    constexpr int KC = 32;
    constexpr int CG = F / 16;
    constexpr int LDA = KC + 8;
    constexpr int ASZ = NORM ? K : 1;
    __shared__ __half As[64 * LDA];
    __shared__ __half Bs[F * LDA];
    __shared__ float as_[ASZ], cs_[ASZ];

    int tid = threadIdx.x;
    if constexpr (NORM) {
        for (int i = tid; i < K; i += NT) { as_[i] = an[i]; cs_[i] = cn[i]; }
        __syncthreads();
    }
    int row0 = blockIdx.x * 64;
    int wid = tid >> 6, lane = tid & 63;
    int quad = lane >> 4, l16 = lane & 15;
    int tr = tid >> 3;
    int tk = (tid & 7) * 4;

    v4f acc[CG];
    #pragma unroll
    for (int g = 0; g < CG; g++) acc[g] = (v4f)0.f;

    for (int k0 = 0; k0 < K; k0 += KC) {
        #pragma unroll
        for (int r = tr; r < 64; r += 32) {
            int row = row0 + r;
            __half h0, h1, h2, h3;
            if (row < N) {
                if constexpr (NORM) {
                    const __half2* xp = (const __half2*)((const __half*)Xv + (size_t)row * K + k0 + tk);
                    float2 v0 = __half22float2(xp[0]);
                    float2 v1 = __half22float2(xp[1]);
                    h0 = __float2half(fmaxf(v0.x * as_[k0 + tk]     + cs_[k0 + tk],     0.f));
                    h1 = __float2half(fmaxf(v0.y * as_[k0 + tk + 1] + cs_[k0 + tk + 1], 0.f));
                    h2 = __float2half(fmaxf(v1.x * as_[k0 + tk + 2] + cs_[k0 + tk + 2], 0.f));
                    h3 = __float2half(fmaxf(v1.y * as_[k0 + tk + 3] + cs_[k0 + tk + 3], 0.f));
                } else {
                    float4 v = *(const float4*)((const float*)Xv + (size_t)row * K + k0 + tk);
                    h0 = __float2half(v.x); h1 = __float2half(v.y);
                    h2 = __float2half(v.z); h3 = __float2half(v.w);
                }
            } else {
                h0 = h1 = h2 = h3 = __float2half(0.f);
            }
            __half2* dst = (__half2*)&As[r * LDA + tk];
            dst[0] = __halves2half2(h0, h1);
            dst[1] = __halves2half2(h2, h3);
        }
        #pragma unroll
        for (int n = tr; n < F; n += 32) {
            const __half2* wp = (const __half2*)(Wt + (size_t)n * K + k0 + tk);
            __half2* dst = (__half2*)&Bs[n * LDA + tk];
            dst[0] = wp[0];
            dst[1] = wp[1];
        }
        __syncthreads();
        v8h a = *(const v8h*)&As[(wid * 16 + l16) * LDA + quad * 8];
        #pragma unroll
        for (int g = 0; g < CG; g++) {
            v8h b = *(const v8h*)&Bs[(g * 16 + l16) * LDA + quad * 8];
            acc[g] = __builtin_amdgcn_mfma_f32_16x16x32_f16(a, b, acc[g], 0, 0, 0);
        }
        __syncthreads();
    }
    #pragma unroll
    for (int reg = 0; reg < 4; reg++) {
        int row = row0 + wid * 16 + quad * 4 + reg;
        if (row < N) {
            float d = dis[row];
            #pragma unroll
            for (int g = 0; g < CG; g++)
                out[(size_t)row * F + g * 16 + l16] = __float2half(d * acc[g][reg]);
        }
    }
}

// ---------------- aggregation: pre[n] = fp16( dis[n]*(hd[n] + sum_{src} hd[src]) + b ) ----------------

template<int F, int U>
__global__ __launch_bounds__(NT) void agg_kernel(const __half* __restrict__ hd, const int* __restrict__ csr,
                                                 const int* __restrict__ row_start, const int* __restrict__ deg,
                                                 const float* __restrict__ dis, const float* __restrict__ b,
                                                 __half* __restrict__ pre, int N) {
    constexpr int H = F / 2;
    constexpr int EPI = 64 / H;
    int wid = (blockIdx.x * NT + threadIdx.x) >> 6;
    int lane = threadIdx.x & 63;
    int fpos = lane % H;
    int sub = lane / H;
    if (wid >= N) return;
    int node = wid;
    int beg = row_start[node];
    int cnt = deg[node];
    const __half2* __restrict__ hd2 = (const __half2*)hd;

    float sx[U], sy[U];
    #pragma unroll
    for (int u = 0; u < U; u++) { sx[u] = 0.f; sy[u] = 0.f; }
    if (sub == 0) {
        float2 f = __half22float2(hd2[(size_t)node * H + fpos]);
        sx[0] = f.x; sy[0] = f.y;
    }
    int i = 0;
    for (; i + EPI * U <= cnt; i += EPI * U) {
        int srcs[U];
        #pragma unroll
        for (int u = 0; u < U; u++) srcs[u] = csr[beg + i + u * EPI + sub];
        #pragma unroll
        for (int u = 0; u < U; u++) {
            float2 f = __half22float2(hd2[(size_t)srcs[u] * H + fpos]);
            sx[u] += f.x; sy[u] += f.y;
        }
    }
    for (; i + sub < cnt; i += EPI) {
        int s = csr[beg + i + sub];
        float2 f = __half22float2(hd2[(size_t)s * H + fpos]);
        sx[0] += f.x; sy[0] += f.y;
    }
    #pragma unroll
    for (int u = 1; u < U; u++) { sx[0] += sx[u]; sy[0] += sy[u]; }
    #pragma unroll
    for (int m = H; m < 64; m <<= 1) {
        sx[0] += __shfl_xor(sx[0], m, 64);
        sy[0] += __shfl_xor(sy[0], m, 64);
    }
    if (sub == 0) {
        float d = dis[node];
        float2 bv = ((const float2*)b)[fpos];
        ((__half2*)pre)[(size_t)node * H + fpos] =
            __floats2half2_rn(d * sx[0] + bv.x, d * sy[0] + bv.y);
    }
}

// ---------------- BN statistics ----------------

template<int F>
__global__ __launch_bounds__(NT) void stats_kernel(const __half* __restrict__ pre, float* __restrict__ S1,
                                                   float* __restrict__ S2, int N) {
    constexpr int RPB = NT / F;
    int tid = threadIdx.x;
    int f = tid % F, r0 = tid / F;
    float s1 = 0.f, s2 = 0.f;
    for (int node = blockIdx.x * RPB + r0; node < N; node += gridDim.x * RPB) {
        float v = __half2float(pre[(size_t)node * F + f]);
        s1 += v; s2 += v * v;
    }
    __shared__ float l1[NT], l2[NT];
    l1[tid] = s1; l2[tid] = s2;
    __syncthreads();
    if (tid < F) {
        #pragma unroll
        for (int j = 1; j < RPB; j++) { s1 += l1[tid + j * F]; s2 += l2[tid + j * F]; }
        atomicAdd(&S1[tid], s1);
        atomicAdd(&S2[tid], s2);
    }
}

__global__ void params_kernel(const float* __restrict__ S1, const float* __restrict__ S2,
                              const float* __restrict__ g, const float* __restrict__ bt,
                              float* __restrict__ a, float* __restrict__ c, int N, int F) {
    int f = threadIdx.x;
    if (f < F) {
        float inv = 1.0f / (float)N;
        float mu = S1[f] * inv;
        float var = fmaxf(S2[f] * inv - mu * mu, 0.f);
        float av = g[f] * rsqrtf(var + EPS);
        a[f] = av;
        c[f] = bt[f] - mu * av;
    }
}

// ---------------- final FC: out[n] = relu(bn3(pre3[n])) @ Wfc + bfc ----------------

__global__ __launch_bounds__(NT) void fc_kernel(const __half* __restrict__ pre, const float* __restrict__ a,
                                                const float* __restrict__ c, const float* __restrict__ wfc,
                                                const float* __restrict__ bfc, float* __restrict__ out, int N) {
    __shared__ float wa[32], wc[32], ww[32];
    int tid = threadIdx.x;
    if (tid < 32) { wa[tid] = a[tid]; wc[tid] = c[tid]; ww[tid] = wfc[tid]; }
    __syncthreads();
    int n = blockIdx.x * NT + tid;
    if (n >= N) return;
    const __half2* p = (const __half2*)(pre + (size_t)n * 32);
    float acc = bfc[0];
    #pragma unroll
    for (int i = 0; i < 16; i++) {
        float2 v = __half22float2(p[i]);
        int f = i * 2;
        acc += fmaxf(v.x * wa[f] + wc[f], 0.f) * ww[f];
        acc += fmaxf(v.y * wa[f + 1] + wc[f + 1], 0.f) * ww[f + 1];
    }
    out[n] = acc;
}

// ---------------- launch ----------------

extern "C" void kernel_launch(void* const* d_in, const int* in_sizes, int n_in,
                              void* d_out, int out_size, void* d_ws, size_t ws_size,
                              hipStream_t stream) {
    const float* x   = (const float*)d_in[0];
    const int*   ei  = (const int*)d_in[1];
    const float* W1  = (const float*)d_in[2];
    const float* b1  = (const float*)d_in[3];
    const float* g1  = (const float*)d_in[4];
    const float* bt1 = (const float*)d_in[5];
    const float* W2  = (const float*)d_in[6];
    const float* b2  = (const float*)d_in[7];
    const float* g2  = (const float*)d_in[8];
    const float* bt2 = (const float*)d_in[9];
    const float* W3  = (const float*)d_in[10];
    const float* b3  = (const float*)d_in[11];
    const float* g3  = (const float*)d_in[12];
    const float* bt3 = (const float*)d_in[13];
    const float* Wfc = (const float*)d_in[14];
    const float* bfc = (const float*)d_in[15];
    float* out = (float*)d_out;

    int N = in_sizes[0] / 256;
    int E = in_sizes[1] / 2;
    const int* src = ei;
    const int* dst = ei + E;
    int NBUK = (N + BNODES - 1) >> BSH;

    char* ws = (char*)d_ws;
    size_t off = 0;
    auto alloc = [&](size_t bytes) -> char* {
        char* p = ws + off;
        off += (bytes + 255) & ~(size_t)255;
        return p;
    };
    __half* bufA     = (__half*)alloc((size_t)N * 128 * 2);
    __half* bufB     = (__half*)alloc((size_t)N * 128 * 2);
    int2*  ebuf      = (int2*)alloc((size_t)E * 8);
    int*   csr       = (int*)alloc((size_t)E * 4);
    int*   deg       = (int*)alloc((size_t)N * 4);
    int*   row_start = (int*)alloc((size_t)N * 4);
    float* dis       = (float*)alloc((size_t)N * 4);
    int*   gbhist    = (int*)alloc((size_t)NBUK * 4);
    int*   bbase     = (int*)alloc((size_t)(NBUK + 1) * 4);
    int*   gcur      = (int*)alloc((size_t)NBUK * 4);
    __half* Wt1      = (__half*)alloc(256 * 128 * 2);
    __half* Wt2      = (__half*)alloc(128 * 64 * 2);
    __half* Wt3      = (__half*)alloc(64 * 32 * 2);
    float* stats = (float*)alloc(448 * 4 * 2);
    float* S1_1 = stats;       float* S2_1 = S1_1 + 128;
    float* S1_2 = S2_1 + 128;  float* S2_2 = S1_2 + 64;
    float* S1_3 = S2_2 + 64;   float* S2_3 = S1_3 + 32;
    float* a1 = S2_3 + 32; float* c1 = a1 + 128;
    float* a2 = c1 + 128;  float* c2 = a2 + 64;
    float* a3 = c2 + 64;   float* c3 = a3 + 32;

    hipMemsetAsync(gbhist, 0, (size_t)NBUK * 4, stream);
    hipMemsetAsync(stats, 0, 448 * 4, stream);

    // CSR build: bucket histogram -> scan -> partition -> per-bucket fill
    bhist_kernel<<<512, NT, 0, stream>>>(dst, gbhist, E, NBUK);
    bscan_kernel<<<1, NT, 0, stream>>>(gbhist, bbase, gcur, E, NBUK);
    part_kernel<<<(E + CH - 1) / CH, NT, 0, stream>>>(src, dst, gcur, ebuf, E, NBUK);
    bfill_kernel<<<NBUK, NT, 0, stream>>>(ebuf, bbase, deg, row_start, dis, csr, N);
    prepw_kernel<<<(256 * 128 + 128 * 64 + 64 * 32 + NT - 1) / NT, NT, 0, stream>>>(W1, W2, W3, Wt1, Wt2, Wt3);

    int GB = (N + 63) / 64;
    int AB = (N + 3) / 4;
    int NB = (N + NT - 1) / NT;
    // layer 1
    mgemm_kernel<256, 128, false><<<GB, NT, 0, stream>>>(x, Wt1, dis, nullptr, nullptr, bufA, N);
    agg_kernel<128, 4><<<AB, NT, 0, stream>>>(bufA, csr, row_start, deg, dis, b1, bufB, N);
    stats_kernel<128><<<256, NT, 0, stream>>>(bufB, S1_1, S2_1, N);
    params_kernel<<<1, 128, 0, stream>>>(S1_1, S2_1, g1, bt1, a1, c1, N, 128);
    // layer 2
    mgemm_kernel<128, 64, true><<<GB, NT, 0, stream>>>(bufB, Wt2, dis, a1, c1, bufA, N);
    agg_kernel<64, 4><<<AB, NT, 0, stream>>>(bufA, csr, row_start, deg, dis, b2, bufB, N);
    stats_kernel<64><<<256, NT, 0, stream>>>(bufB, S1_2, S2_2, N);
    params_kernel<<<1, 64, 0, stream>>>(S1_2, S2_2, g2, bt2, a2, c2, N, 64);
    // layer 3
    mgemm_kernel<64, 32, true><<<GB, NT, 0, stream>>>(bufB, Wt3, dis, a2, c2, bufA, N);
    agg_kernel<32, 2><<<AB, NT, 0, stream>>>(bufA, csr, row_start, deg, dis, b3, bufB, N);
    stats_kernel<32><<<256, NT, 0, stream>>>(bufB, S1_3, S2_3, N);
    params_kernel<<<1, 32, 0, stream>>>(S1_3, S2_3, g3, bt3, a3, c3, N, 32);
    // head
    fc_kernel<<<NB, NT, 0, stream>>>(bufB, a3, c3, Wfc, bfc, out, N);
}

// Round 5
// 631.061 us; speedup vs baseline: 2.0835x; 1.0832x over previous
//
#include <hip/hip_runtime.h>
#include <hip/hip_fp16.h>

#define EPS 1e-5f
constexpr int NT = 256;
constexpr int BSH = 9;            // bucket = dst >> 9 (512 nodes per bucket)
constexpr int BNODES = 1 << BSH;
constexpr int CH = 4096;          // edges per partition block

typedef _Float16 v8h __attribute__((ext_vector_type(8)));
typedef float v4f __attribute__((ext_vector_type(4)));

// ---------------- bucket histogram (LDS-staged) ----------------

__global__ __launch_bounds__(NT) void bhist_kernel(const int* __restrict__ dst, int* __restrict__ gbhist,
                                                   int E, int NBUK) {
    __shared__ int h[512];
    int tid = threadIdx.x;
    for (int i = tid; i < 512; i += NT) h[i] = 0;
    __syncthreads();
    for (int e = blockIdx.x * NT + tid; e < E; e += gridDim.x * NT)
        atomicAdd(&h[dst[e] >> BSH], 1);
    __syncthreads();
    for (int i = tid; i < NBUK; i += NT)
        if (h[i]) atomicAdd(&gbhist[i], h[i]);
}

// ---------------- bucket scan: bbase[0..NBUK] (exclusive), gcur = bbase ----------------

__global__ __launch_bounds__(NT) void bscan_kernel(const int* __restrict__ gbhist, int* __restrict__ bbase,
                                                   int* __restrict__ gcur, int E, int NBUK) {
    __shared__ int wsum[5];
    int tid = threadIdx.x;
    int lane = tid & 63, wid = tid >> 6;
    int e0 = (2 * tid < NBUK) ? gbhist[2 * tid] : 0;
    int e1 = (2 * tid + 1 < NBUK) ? gbhist[2 * tid + 1] : 0;
    int u = e0 + e1;
    int incl = u;
    #pragma unroll
    for (int off = 1; off < 64; off <<= 1) {
        int t = __shfl_up(incl, off, 64);
        if (lane >= off) incl += t;
    }
    if (lane == 63) wsum[wid] = incl;
    __syncthreads();
    if (tid == 0) { int s = 0; for (int w = 0; w < 4; w++) { int t = wsum[w]; wsum[w] = s; s += t; } }
    __syncthreads();
    int base = wsum[wid] + incl - u;
    if (2 * tid < NBUK)     { bbase[2 * tid] = base;          gcur[2 * tid] = base; }
    if (2 * tid + 1 < NBUK) { bbase[2 * tid + 1] = base + e0; gcur[2 * tid + 1] = base + e0; }
    if (tid == 0) bbase[NBUK] = E;
}

// ---------------- phase 1: partition edges into ebuf by bucket (block-local counting sort) ----------------
// ebuf entry: (dst & 511) << 18 | src   (N < 2^18)

__global__ __launch_bounds__(NT) void part_kernel(const int* __restrict__ src, const int* __restrict__ dst,
                                                  int* __restrict__ gcur, int* __restrict__ ebuf,
                                                  int E, int NBUK) {
    constexpr int EPT = CH / NT;   // 16 edges per thread
    __shared__ int hist[512];
    __shared__ int lscan[512];
    __shared__ int gbase[512];
    __shared__ int2 stage[CH];
    int tid = threadIdx.x;
    int lane = tid & 63;
    int e0 = blockIdx.x * CH;

    for (int i = tid; i < 512; i += NT) hist[i] = 0;
    __syncthreads();

    int2 ed[EPT]; int rank[EPT]; int buk[EPT];
    #pragma unroll
    for (int j = 0; j < EPT; j++) {
        int e = e0 + j * NT + tid;
        if (e < E) {
            ed[j].x = src[e]; ed[j].y = dst[e];
            buk[j] = ed[j].y >> BSH;
            rank[j] = atomicAdd(&hist[buk[j]], 1);
        } else buk[j] = -1;
    }
    __syncthreads();
    if (tid < 64) {
        int bi = tid * 8;
        int v[8]; int s = 0;
        #pragma unroll
        for (int j = 0; j < 8; j++) { v[j] = s; s += hist[bi + j]; }
        int incl = s;
        #pragma unroll
        for (int off = 1; off < 64; off <<= 1) {
            int t = __shfl_up(incl, off, 64);
            if (lane >= off) incl += t;
        }
        int lb = incl - s;
        #pragma unroll
        for (int j = 0; j < 8; j++) lscan[bi + j] = lb + v[j];
    }
    __syncthreads();
    for (int i = tid; i < NBUK; i += NT) {
        int c = hist[i];
        gbase[i] = c ? atomicAdd(&gcur[i], c) : 0;
    }
    #pragma unroll
    for (int j = 0; j < EPT; j++)
        if (buk[j] >= 0) stage[lscan[buk[j]] + rank[j]] = ed[j];
    __syncthreads();
    int cnt = min(E - e0, CH);
    for (int i = tid; i < cnt; i += NT) {
        int2 e = stage[i];
        int b = e.y >> BSH;
        ebuf[gbase[b] + (i - lscan[b])] = ((e.y & (BNODES - 1)) << 18) | e.x;
    }
}

// ---------------- phase 2: per-bucket deg/row_start/dis + csr fill (L2-local scatter) ----------------

__global__ __launch_bounds__(NT) void bfill_kernel(const int* __restrict__ ebuf, const int* __restrict__ bbase,
                                                   int* __restrict__ deg, int* __restrict__ row_start,
                                                   float* __restrict__ dis, int* __restrict__ csr, int N) {
    __shared__ int ldeg[BNODES];
    __shared__ int lrs[BNODES];
    __shared__ int wsum[5];
    int tid = threadIdx.x;
    int lane = tid & 63, wid = tid >> 6;
    int b = blockIdx.x;
    int node0 = b << BSH;
    int nn = min(BNODES, N - node0);
    int beg = bbase[b], end = bbase[b + 1];

    for (int i = tid; i < BNODES; i += NT) ldeg[i] = 0;
    __syncthreads();
    for (int i = beg + tid; i < end; i += NT)
        atomicAdd(&ldeg[ebuf[i] >> 18], 1);
    __syncthreads();
    int e0 = ldeg[2 * tid], e1 = ldeg[2 * tid + 1];
    int u = e0 + e1;
    int incl = u;
    #pragma unroll
    for (int off = 1; off < 64; off <<= 1) {
        int t = __shfl_up(incl, off, 64);
        if (lane >= off) incl += t;
    }
    if (lane == 63) wsum[wid] = incl;
    __syncthreads();
    if (tid == 0) { int s = 0; for (int w = 0; w < 4; w++) { int t = wsum[w]; wsum[w] = s; s += t; } }
    __syncthreads();
    int base = wsum[wid] + incl - u;
    lrs[2 * tid] = base;
    lrs[2 * tid + 1] = base + e0;
    __syncthreads();
    for (int i = tid; i < nn; i += NT) {
        int dg = ldeg[i];
        deg[node0 + i] = dg;
        row_start[node0 + i] = beg + lrs[i];
        dis[node0 + i] = rsqrtf((float)dg + 1.0f);
    }
    __syncthreads();
    for (int i = tid; i < BNODES; i += NT) ldeg[i] = 0;   // reuse as cursor
    __syncthreads();
    for (int i = beg + tid; i < end; i += NT) {
        int code = ebuf[i];
        int l = code >> 18;
        int off = atomicAdd(&ldeg[l], 1);
        csr[beg + lrs[l] + off] = code & 0x3FFFF;
    }
}

// ---------------- weight prep: W fp32 [K][F] -> Wt fp16 [F][K] (transposed) ----------------

__global__ __launch_bounds__(NT) void prepw_kernel(const float* __restrict__ W1, const float* __restrict__ W2,
                                                   const float* __restrict__ W3, __half* __restrict__ Wt1,
                                                   __half* __restrict__ Wt2, __half* __restrict__ Wt3) {
    int i = blockIdx.x * NT + threadIdx.x;
    if (i < 256 * 128) {
        int k = i >> 7, f = i & 127;
        Wt1[f * 256 + k] = __float2half(W1[i]);
    } else if (i < 256 * 128 + 128 * 64) {
        int j = i - 256 * 128; int k = j >> 6, f = j & 63;
        Wt2[f * 128 + k] = __float2half(W2[j]);
    } else if (i < 256 * 128 + 128 * 64 + 64 * 32) {
        int j = i - 256 * 128 - 128 * 64; int k = j >> 5, f = j & 31;
        Wt3[f * 64 + k] = __float2half(W3[j]);
    }
}

// ---------------- MFMA GEMM: out[row] = fp16( dis[row] * (norm(X)[row] @ W) ) ----------------

template<int K, int F, bool NORM>
__global__ __launch_bounds__(NT) void mgemm_kernel(const void* __restrict__ Xv, const __half* __restrict__ Wt,
                                                   const float* __restrict__ dis, const float* __restrict__ an,
                                                   const float* __restrict__ cn, __half* __restrict__ out, int N) {
    constexpr int KC = 32;
    constexpr int CG = F / 16;
    constexpr int LDA = KC + 8;
    constexpr int ASZ = NORM ? K : 1;
    __shared__ __half As[64 * LDA];
    __shared__ __half Bs[F * LDA];
    __shared__ float as_[ASZ], cs_[ASZ];

    int tid = threadIdx.x;
    if constexpr (NORM) {
        for (int i = tid; i < K; i += NT) { as_[i] = an[i]; cs_[i] = cn[i]; }
        __syncthreads();
    }
    int row0 = blockIdx.x * 64;
    int wid = tid >> 6, lane = tid & 63;
    int quad = lane >> 4, l16 = lane & 15;
    int tr = tid >> 3;
    int tk = (tid & 7) * 4;

    v4f acc[CG];
    #pragma unroll
    for (int g = 0; g < CG; g++) acc[g] = (v4f)0.f;

    for (int k0 = 0; k0 < K; k0 += KC) {
        #pragma unroll
        for (int r = tr; r < 64; r += 32) {
            int row = row0 + r;
            __half h0, h1, h2, h3;
            if (row < N) {
                if constexpr (NORM) {
                    const __half2* xp = (const __half2*)((const __half*)Xv + (size_t)row * K + k0 + tk);
                    float2 v0 = __half22float2(xp[0]);
                    float2 v1 = __half22float2(xp[1]);
                    h0 = __float2half(fmaxf(v0.x * as_[k0 + tk]     + cs_[k0 + tk],     0.f));
                    h1 = __float2half(fmaxf(v0.y * as_[k0 + tk + 1] + cs_[k0 + tk + 1], 0.f));
                    h2 = __float2half(fmaxf(v1.x * as_[k0 + tk + 2] + cs_[k0 + tk + 2], 0.f));
                    h3 = __float2half(fmaxf(v1.y * as_[k0 + tk + 3] + cs_[k0 + tk + 3], 0.f));
                } else {
                    float4 v = *(const float4*)((const float*)Xv + (size_t)row * K + k0 + tk);
                    h0 = __float2half(v.x); h1 = __float2half(v.y);
                    h2 = __float2half(v.z); h3 = __float2half(v.w);
                }
            } else {
                h0 = h1 = h2 = h3 = __float2half(0.f);
            }
            __half2* dst = (__half2*)&As[r * LDA + tk];
            dst[0] = __halves2half2(h0, h1);
            dst[1] = __halves2half2(h2, h3);
        }
        #pragma unroll
        for (int n = tr; n < F; n += 32) {
            const __half2* wp = (const __half2*)(Wt + (size_t)n * K + k0 + tk);
            __half2* dst = (__half2*)&Bs[n * LDA + tk];
            dst[0] = wp[0];
            dst[1] = wp[1];
        }
        __syncthreads();
        v8h a = *(const v8h*)&As[(wid * 16 + l16) * LDA + quad * 8];
        #pragma unroll
        for (int g = 0; g < CG; g++) {
            v8h b = *(const v8h*)&Bs[(g * 16 + l16) * LDA + quad * 8];
            acc[g] = __builtin_amdgcn_mfma_f32_16x16x32_f16(a, b, acc[g], 0, 0, 0);
        }
        __syncthreads();
    }
    #pragma unroll
    for (int reg = 0; reg < 4; reg++) {
        int row = row0 + wid * 16 + quad * 4 + reg;
        if (row < N) {
            float d = dis[row];
            #pragma unroll
            for (int g = 0; g < CG; g++)
                out[(size_t)row * F + g * 16 + l16] = __float2half(d * acc[g][reg]);
        }
    }
}

// ---------------- aggregation: pre[n] = fp16( dis[n]*(hd[n] + sum_{src} hd[src]) + b ) ----------------
// One wave per node, 16 B/lane gathers: LR = F/8 lanes per row, SUBS = 64/LR edges per iteration.

__device__ __forceinline__ void addh2(float* a, int4 v) {
    float2 f0 = __half22float2(*(__half2*)&v.x);
    float2 f1 = __half22float2(*(__half2*)&v.y);
    float2 f2 = __half22float2(*(__half2*)&v.z);
    float2 f3 = __half22float2(*(__half2*)&v.w);
    a[0] += f0.x; a[1] += f0.y; a[2] += f1.x; a[3] += f1.y;
    a[4] += f2.x; a[5] += f2.y; a[6] += f3.x; a[7] += f3.y;
}

template<int F, int U>
__global__ __launch_bounds__(NT) void agg_kernel(const __half* __restrict__ hd, const int* __restrict__ csr,
                                                 const int* __restrict__ row_start, const int* __restrict__ deg,
                                                 const float* __restrict__ dis, const float* __restrict__ b,
                                                 __half* __restrict__ pre, int N) {
    constexpr int LR = F / 8;      // lanes per row (16 B each)
    constexpr int SUBS = 64 / LR;  // rows gathered per wave-iteration
    int node = (blockIdx.x * NT + threadIdx.x) >> 6;
    int lane = threadIdx.x & 63;
    int fl = lane % LR, sub = lane / LR;
    if (node >= N) return;
    int beg = row_start[node], cnt = deg[node];

    float acc[U][8];
    #pragma unroll
    for (int u = 0; u < U; u++)
        #pragma unroll
        for (int j = 0; j < 8; j++) acc[u][j] = 0.f;

    int i = 0;
    for (; i + SUBS * U <= cnt; i += SUBS * U) {
        int s[U];
        #pragma unroll
        for (int u = 0; u < U; u++) s[u] = csr[beg + i + u * SUBS + sub];
        #pragma unroll
        for (int u = 0; u < U; u++) {
            int4 v = *(const int4*)(hd + (size_t)s[u] * F + fl * 8);
            addh2(acc[u], v);
        }
    }
    for (; i + sub < cnt; i += SUBS) {
        int s = csr[beg + i + sub];
        int4 v = *(const int4*)(hd + (size_t)s * F + fl * 8);
        addh2(acc[0], v);
    }
    if (sub == 0) {
        int4 v = *(const int4*)(hd + (size_t)node * F + fl * 8);
        addh2(acc[0], v);
    }
    #pragma unroll
    for (int u = 1; u < U; u++)
        #pragma unroll
        for (int j = 0; j < 8; j++) acc[0][j] += acc[u][j];
    #pragma unroll
    for (int m = LR; m < 64; m <<= 1)
        #pragma unroll
        for (int j = 0; j < 8; j++) acc[0][j] += __shfl_xor(acc[0][j], m, 64);
    if (sub == 0) {
        float d = dis[node];
        float4 b0 = *(const float4*)(b + fl * 8);
        float4 b1 = *(const float4*)(b + fl * 8 + 4);
        __half2 h[4];
        h[0] = __floats2half2_rn(d * acc[0][0] + b0.x, d * acc[0][1] + b0.y);
        h[1] = __floats2half2_rn(d * acc[0][2] + b0.z, d * acc[0][3] + b0.w);
        h[2] = __floats2half2_rn(d * acc[0][4] + b1.x, d * acc[0][5] + b1.y);
        h[3] = __floats2half2_rn(d * acc[0][6] + b1.z, d * acc[0][7] + b1.w);
        *(int4*)(pre + (size_t)node * F + fl * 8) = *(int4*)h;
    }
}

// ---------------- BN statistics ----------------

template<int F>
__global__ __launch_bounds__(NT) void stats_kernel(const __half* __restrict__ pre, float* __restrict__ S1,
                                                   float* __restrict__ S2, int N) {
    constexpr int FP = F / 2;
    constexpr int RPB = NT / FP;
    int tid = threadIdx.x;
    int f = tid % FP, r0 = tid / FP;
    float s1x = 0.f, s1y = 0.f, s2x = 0.f, s2y = 0.f;
    const __half2* p2 = (const __half2*)pre;
    for (int node = blockIdx.x * RPB + r0; node < N; node += gridDim.x * RPB) {
        float2 v = __half22float2(p2[(size_t)node * FP + f]);
        s1x += v.x; s1y += v.y; s2x += v.x * v.x; s2y += v.y * v.y;
    }
    __shared__ float l1x[NT], l1y[NT], l2x[NT], l2y[NT];
    l1x[tid] = s1x; l1y[tid] = s1y; l2x[tid] = s2x; l2y[tid] = s2y;
    __syncthreads();
    if (tid < FP) {
        #pragma unroll
        for (int j = 1; j < RPB; j++) {
            s1x += l1x[tid + j * FP]; s1y += l1y[tid + j * FP];
            s2x += l2x[tid + j * FP]; s2y += l2y[tid + j * FP];
        }
        atomicAdd(&S1[2 * tid], s1x); atomicAdd(&S1[2 * tid + 1], s1y);
        atomicAdd(&S2[2 * tid], s2x); atomicAdd(&S2[2 * tid + 1], s2y);
    }
}

__global__ void params_kernel(const float* __restrict__ S1, const float* __restrict__ S2,
                              const float* __restrict__ g, const float* __restrict__ bt,
                              float* __restrict__ a, float* __restrict__ c, int N, int F) {
    int f = threadIdx.x;
    if (f < F) {
        float inv = 1.0f / (float)N;
        float mu = S1[f] * inv;
        float var = fmaxf(S2[f] * inv - mu * mu, 0.f);
        float av = g[f] * rsqrtf(var + EPS);
        a[f] = av;
        c[f] = bt[f] - mu * av;
    }
}

// ---------------- final FC: out[n] = relu(bn3(pre3[n])) @ Wfc + bfc ----------------

__global__ __launch_bounds__(NT) void fc_kernel(const __half* __restrict__ pre, const float* __restrict__ a,
                                                const float* __restrict__ c, const float* __restrict__ wfc,
                                                const float* __restrict__ bfc, float* __restrict__ out, int N) {
    __shared__ float wa[32], wc[32], ww[32];
    int tid = threadIdx.x;
    if (tid < 32) { wa[tid] = a[tid]; wc[tid] = c[tid]; ww[tid] = wfc[tid]; }
    __syncthreads();
    int n = blockIdx.x * NT + tid;
    if (n >= N) return;
    const __half2* p = (const __half2*)(pre + (size_t)n * 32);
    float acc = bfc[0];
    #pragma unroll
    for (int i = 0; i < 16; i++) {
        float2 v = __half22float2(p[i]);
        int f = i * 2;
        acc += fmaxf(v.x * wa[f] + wc[f], 0.f) * ww[f];
        acc += fmaxf(v.y * wa[f + 1] + wc[f + 1], 0.f) * ww[f + 1];
    }
    out[n] = acc;
}

// ---------------- launch ----------------

extern "C" void kernel_launch(void* const* d_in, const int* in_sizes, int n_in,
                              void* d_out, int out_size, void* d_ws, size_t ws_size,
                              hipStream_t stream) {
    const float* x   = (const float*)d_in[0];
    const int*   ei  = (const int*)d_in[1];
    const float* W1  = (const float*)d_in[2];
    const float* b1  = (const float*)d_in[3];
    const float* g1  = (const float*)d_in[4];
    const float* bt1 = (const float*)d_in[5];
    const float* W2  = (const float*)d_in[6];
    const float* b2  = (const float*)d_in[7];
    const float* g2  = (const float*)d_in[8];
    const float* bt2 = (const float*)d_in[9];
    const float* W3  = (const float*)d_in[10];
    const float* b3  = (const float*)d_in[11];
    const float* g3  = (const float*)d_in[12];
    const float* bt3 = (const float*)d_in[13];
    const float* Wfc = (const float*)d_in[14];
    const float* bfc = (const float*)d_in[15];
    float* out = (float*)d_out;

    int N = in_sizes[0] / 256;
    int E = in_sizes[1] / 2;
    const int* src = ei;
    const int* dst = ei + E;
    int NBUK = (N + BNODES - 1) >> BSH;

    char* ws = (char*)d_ws;
    size_t off = 0;
    auto alloc = [&](size_t bytes) -> char* {
        char* p = ws + off;
        off += (bytes + 255) & ~(size_t)255;
        return p;
    };
    __half* bufA     = (__half*)alloc((size_t)N * 128 * 2);
    __half* bufB     = (__half*)alloc((size_t)N * 128 * 2);
    int*   ebuf      = (int*)alloc((size_t)E * 4);
    int*   csr       = (int*)alloc((size_t)E * 4);
    int*   deg       = (int*)alloc((size_t)N * 4);
    int*   row_start = (int*)alloc((size_t)N * 4);
    float* dis       = (float*)alloc((size_t)N * 4);
    int*   gbhist    = (int*)alloc((size_t)NBUK * 4);
    int*   bbase     = (int*)alloc((size_t)(NBUK + 1) * 4);
    int*   gcur      = (int*)alloc((size_t)NBUK * 4);
    __half* Wt1      = (__half*)alloc(256 * 128 * 2);
    __half* Wt2      = (__half*)alloc(128 * 64 * 2);
    __half* Wt3      = (__half*)alloc(64 * 32 * 2);
    float* stats = (float*)alloc(448 * 4 * 2);
    float* S1_1 = stats;       float* S2_1 = S1_1 + 128;
    float* S1_2 = S2_1 + 128;  float* S2_2 = S1_2 + 64;
    float* S1_3 = S2_2 + 64;   float* S2_3 = S1_3 + 32;
    float* a1 = S2_3 + 32; float* c1 = a1 + 128;
    float* a2 = c1 + 128;  float* c2 = a2 + 64;
    float* a3 = c2 + 64;   float* c3 = a3 + 32;

    hipMemsetAsync(gbhist, 0, (size_t)NBUK * 4, stream);
    hipMemsetAsync(stats, 0, 448 * 4, stream);

    // CSR build: bucket histogram -> scan -> partition -> per-bucket fill
    bhist_kernel<<<512, NT, 0, stream>>>(dst, gbhist, E, NBUK);
    bscan_kernel<<<1, NT, 0, stream>>>(gbhist, bbase, gcur, E, NBUK);
    part_kernel<<<(E + CH - 1) / CH, NT, 0, stream>>>(src, dst, gcur, ebuf, E, NBUK);
    bfill_kernel<<<NBUK, NT, 0, stream>>>(ebuf, bbase, deg, row_start, dis, csr, N);
    prepw_kernel<<<(256 * 128 + 128 * 64 + 64 * 32 + NT - 1) / NT, NT, 0, stream>>>(W1, W2, W3, Wt1, Wt2, Wt3);

    int GB = (N + 63) / 64;
    int AB = (N + 3) / 4;   // one wave per node, 4 nodes per block
    int NB = (N + NT - 1) / NT;
    // layer 1
    mgemm_kernel<256, 128, false><<<GB, NT, 0, stream>>>(x, Wt1, dis, nullptr, nullptr, bufA, N);
    agg_kernel<128, 4><<<AB, NT, 0, stream>>>(bufA, csr, row_start, deg, dis, b1, bufB, N);
    stats_kernel<128><<<256, NT, 0, stream>>>(bufB, S1_1, S2_1, N);
    params_kernel<<<1, 128, 0, stream>>>(S1_1, S2_1, g1, bt1, a1, c1, N, 128);
    // layer 2
    mgemm_kernel<128, 64, true><<<GB, NT, 0, stream>>>(bufB, Wt2, dis, a1, c1, bufA, N);
    agg_kernel<64, 2><<<AB, NT, 0, stream>>>(bufA, csr, row_start, deg, dis, b2, bufB, N);
    stats_kernel<64><<<256, NT, 0, stream>>>(bufB, S1_2, S2_2, N);
    params_kernel<<<1, 64, 0, stream>>>(S1_2, S2_2, g2, bt2, a2, c2, N, 64);
    // layer 3
    mgemm_kernel<64, 32, true><<<GB, NT, 0, stream>>>(bufB, Wt3, dis, a2, c2, bufA, N);
    agg_kernel<32, 1><<<AB, NT, 0, stream>>>(bufA, csr, row_start, deg, dis, b3, bufB, N);
    stats_kernel<32><<<256, NT, 0, stream>>>(bufB, S1_3, S2_3, N);
    params_kernel<<<1, 32, 0, stream>>>(S1_3, S2_3, g3, bt3, a3, c3, N, 32);
    // head
    fc_kernel<<<NB, NT, 0, stream>>>(bufB, a3, c3, Wfc, bfc, out, N);
}

// Round 6
// 623.139 us; speedup vs baseline: 2.1100x; 1.0127x over previous
//
#include <hip/hip_runtime.h>
#include <hip/hip_fp16.h>

#define EPS 1e-5f
constexpr int NT = 256;
constexpr int BSH = 9;            // bucket = dst >> 9 (512 nodes per bucket)
constexpr int BNODES = 1 << BSH;
constexpr int CH = 4096;          // edges per partition block

typedef _Float16 v8h __attribute__((ext_vector_type(8)));
typedef float v4f __attribute__((ext_vector_type(4)));

// ---------------- bucket histogram (LDS-staged) ----------------

__global__ __launch_bounds__(NT) void bhist_kernel(const int* __restrict__ dst, int* __restrict__ gbhist,
                                                   int E, int NBUK) {
    __shared__ int h[512];
    int tid = threadIdx.x;
    for (int i = tid; i < 512; i += NT) h[i] = 0;
    __syncthreads();
    for (int e = blockIdx.x * NT + tid; e < E; e += gridDim.x * NT)
        atomicAdd(&h[dst[e] >> BSH], 1);
    __syncthreads();
    for (int i = tid; i < NBUK; i += NT)
        if (h[i]) atomicAdd(&gbhist[i], h[i]);
}

// ---------------- bucket scan: bbase[0..NBUK] (exclusive), gcur = bbase ----------------

__global__ __launch_bounds__(NT) void bscan_kernel(const int* __restrict__ gbhist, int* __restrict__ bbase,
                                                   int* __restrict__ gcur, int E, int NBUK) {
    __shared__ int wsum[5];
    int tid = threadIdx.x;
    int lane = tid & 63, wid = tid >> 6;
    int e0 = (2 * tid < NBUK) ? gbhist[2 * tid] : 0;
    int e1 = (2 * tid + 1 < NBUK) ? gbhist[2 * tid + 1] : 0;
    int u = e0 + e1;
    int incl = u;
    #pragma unroll
    for (int off = 1; off < 64; off <<= 1) {
        int t = __shfl_up(incl, off, 64);
        if (lane >= off) incl += t;
    }
    if (lane == 63) wsum[wid] = incl;
    __syncthreads();
    if (tid == 0) { int s = 0; for (int w = 0; w < 4; w++) { int t = wsum[w]; wsum[w] = s; s += t; } }
    __syncthreads();
    int base = wsum[wid] + incl - u;
    if (2 * tid < NBUK)     { bbase[2 * tid] = base;          gcur[2 * tid] = base; }
    if (2 * tid + 1 < NBUK) { bbase[2 * tid + 1] = base + e0; gcur[2 * tid + 1] = base + e0; }
    if (tid == 0) bbase[NBUK] = E;
}

// ---------------- phase 1: partition edges into ebuf by bucket (block-local counting sort) ----------------
// ebuf entry: (dst & 511) << 18 | src   (N < 2^18)

__global__ __launch_bounds__(NT) void part_kernel(const int* __restrict__ src, const int* __restrict__ dst,
                                                  int* __restrict__ gcur, int* __restrict__ ebuf,
                                                  int E, int NBUK) {
    constexpr int EPT = CH / NT;   // 16 edges per thread
    __shared__ int hist[512];
    __shared__ int lscan[512];
    __shared__ int gbase[512];
    __shared__ int2 stage[CH];
    int tid = threadIdx.x;
    int lane = tid & 63;
    int e0 = blockIdx.x * CH;

    for (int i = tid; i < 512; i += NT) hist[i] = 0;
    __syncthreads();

    int2 ed[EPT]; int rank[EPT]; int buk[EPT];
    #pragma unroll
    for (int j = 0; j < EPT; j++) {
        int e = e0 + j * NT + tid;
        if (e < E) {
            ed[j].x = src[e]; ed[j].y = dst[e];
            buk[j] = ed[j].y >> BSH;
            rank[j] = atomicAdd(&hist[buk[j]], 1);
        } else buk[j] = -1;
    }
    __syncthreads();
    if (tid < 64) {
        int bi = tid * 8;
        int v[8]; int s = 0;
        #pragma unroll
        for (int j = 0; j < 8; j++) { v[j] = s; s += hist[bi + j]; }
        int incl = s;
        #pragma unroll
        for (int off = 1; off < 64; off <<= 1) {
            int t = __shfl_up(incl, off, 64);
            if (lane >= off) incl += t;
        }
        int lb = incl - s;
        #pragma unroll
        for (int j = 0; j < 8; j++) lscan[bi + j] = lb + v[j];
    }
    __syncthreads();
    for (int i = tid; i < NBUK; i += NT) {
        int c = hist[i];
        gbase[i] = c ? atomicAdd(&gcur[i], c) : 0;
    }
    #pragma unroll
    for (int j = 0; j < EPT; j++)
        if (buk[j] >= 0) stage[lscan[buk[j]] + rank[j]] = ed[j];
    __syncthreads();
    int cnt = min(E - e0, CH);
    for (int i = tid; i < cnt; i += NT) {
        int2 e = stage[i];
        int b = e.y >> BSH;
        ebuf[gbase[b] + (i - lscan[b])] = ((e.y & (BNODES - 1)) << 18) | e.x;
    }
}

// ---------------- phase 2: per-bucket row_start/dis + csr fill (L2-local scatter) ----------------

__global__ __launch_bounds__(NT) void bfill_kernel(const int* __restrict__ ebuf, const int* __restrict__ bbase,
                                                   int* __restrict__ row_start,
                                                   float* __restrict__ dis, int* __restrict__ csr, int N) {
    __shared__ int ldeg[BNODES];
    __shared__ int lrs[BNODES];
    __shared__ int wsum[5];
    int tid = threadIdx.x;
    int lane = tid & 63, wid = tid >> 6;
    int b = blockIdx.x;
    int node0 = b << BSH;
    int nn = min(BNODES, N - node0);
    int beg = bbase[b], end = bbase[b + 1];

    for (int i = tid; i < BNODES; i += NT) ldeg[i] = 0;
    __syncthreads();
    for (int i = beg + tid; i < end; i += NT)
        atomicAdd(&ldeg[ebuf[i] >> 18], 1);
    __syncthreads();
    int e0 = ldeg[2 * tid], e1 = ldeg[2 * tid + 1];
    int u = e0 + e1;
    int incl = u;
    #pragma unroll
    for (int off = 1; off < 64; off <<= 1) {
        int t = __shfl_up(incl, off, 64);
        if (lane >= off) incl += t;
    }
    if (lane == 63) wsum[wid] = incl;
    __syncthreads();
    if (tid == 0) { int s = 0; for (int w = 0; w < 4; w++) { int t = wsum[w]; wsum[w] = s; s += t; } }
    __syncthreads();
    int base = wsum[wid] + incl - u;
    lrs[2 * tid] = base;
    lrs[2 * tid + 1] = base + e0;
    __syncthreads();
    for (int i = tid; i < nn; i += NT) {
        int dg = ldeg[i];
        row_start[node0 + i] = beg + lrs[i];
        dis[node0 + i] = rsqrtf((float)dg + 1.0f);
    }
    if (b == gridDim.x - 1 && tid == 0) row_start[N] = end;
    __syncthreads();
    for (int i = tid; i < BNODES; i += NT) ldeg[i] = 0;   // reuse as cursor
    __syncthreads();
    for (int i = beg + tid; i < end; i += NT) {
        int code = ebuf[i];
        int l = code >> 18;
        int off = atomicAdd(&ldeg[l], 1);
        csr[beg + lrs[l] + off] = code & 0x3FFFF;
    }
}

// ---------------- weight prep: W fp32 [K][F] -> Wt fp16 [F][K] (transposed) ----------------

__global__ __launch_bounds__(NT) void prepw_kernel(const float* __restrict__ W1, const float* __restrict__ W2,
                                                   const float* __restrict__ W3, __half* __restrict__ Wt1,
                                                   __half* __restrict__ Wt2, __half* __restrict__ Wt3) {
    int i = blockIdx.x * NT + threadIdx.x;
    if (i < 256 * 128) {
        int k = i >> 7, f = i & 127;
        Wt1[f * 256 + k] = __float2half(W1[i]);
    } else if (i < 256 * 128 + 128 * 64) {
        int j = i - 256 * 128; int k = j >> 6, f = j & 63;
        Wt2[f * 128 + k] = __float2half(W2[j]);
    } else if (i < 256 * 128 + 128 * 64 + 64 * 32) {
        int j = i - 256 * 128 - 128 * 64; int k = j >> 5, f = j & 31;
        Wt3[f * 64 + k] = __float2half(W3[j]);
    }
}

// ---------------- MFMA GEMM: out[row] = fp16( dis[row] * (norm(X)[row] @ W) ) ----------------

template<int K, int F, bool NORM>
__global__ __launch_bounds__(NT) void mgemm_kernel(const void* __restrict__ Xv, const __half* __restrict__ Wt,
                                                   const float* __restrict__ dis, const float* __restrict__ an,
                                                   const float* __restrict__ cn, __half* __restrict__ out, int N) {
    constexpr int KC = 32;
    constexpr int CG = F / 16;
    constexpr int LDA = KC + 8;
    constexpr int ASZ = NORM ? K : 1;
    __shared__ __half As[64 * LDA];
    __shared__ __half Bs[F * LDA];
    __shared__ float as_[ASZ], cs_[ASZ];

    int tid = threadIdx.x;
    if constexpr (NORM) {
        for (int i = tid; i < K; i += NT) { as_[i] = an[i]; cs_[i] = cn[i]; }
        __syncthreads();
    }
    int row0 = blockIdx.x * 64;
    int wid = tid >> 6, lane = tid & 63;
    int quad = lane >> 4, l16 = lane & 15;
    int tr = tid >> 3;
    int tk = (tid & 7) * 4;

    v4f acc[CG];
    #pragma unroll
    for (int g = 0; g < CG; g++) acc[g] = (v4f)0.f;

    for (int k0 = 0; k0 < K; k0 += KC) {
        #pragma unroll
        for (int r = tr; r < 64; r += 32) {
            int row = row0 + r;
            __half h0, h1, h2, h3;
            if (row < N) {
                if constexpr (NORM) {
                    const __half2* xp = (const __half2*)((const __half*)Xv + (size_t)row * K + k0 + tk);
                    float2 v0 = __half22float2(xp[0]);
                    float2 v1 = __half22float2(xp[1]);
                    h0 = __float2half(fmaxf(v0.x * as_[k0 + tk]     + cs_[k0 + tk],     0.f));
                    h1 = __float2half(fmaxf(v0.y * as_[k0 + tk + 1] + cs_[k0 + tk + 1], 0.f));
                    h2 = __float2half(fmaxf(v1.x * as_[k0 + tk + 2] + cs_[k0 + tk + 2], 0.f));
                    h3 = __float2half(fmaxf(v1.y * as_[k0 + tk + 3] + cs_[k0 + tk + 3], 0.f));
                } else {
                    float4 v = *(const float4*)((const float*)Xv + (size_t)row * K + k0 + tk);
                    h0 = __float2half(v.x); h1 = __float2half(v.y);
                    h2 = __float2half(v.z); h3 = __float2half(v.w);
                }
            } else {
                h0 = h1 = h2 = h3 = __float2half(0.f);
            }
            __half2* dst = (__half2*)&As[r * LDA + tk];
            dst[0] = __halves2half2(h0, h1);
            dst[1] = __halves2half2(h2, h3);
        }
        #pragma unroll
        for (int n = tr; n < F; n += 32) {
            const __half2* wp = (const __half2*)(Wt + (size_t)n * K + k0 + tk);
            __half2* dst = (__half2*)&Bs[n * LDA + tk];
            dst[0] = wp[0];
            dst[1] = wp[1];
        }
        __syncthreads();
        v8h a = *(const v8h*)&As[(wid * 16 + l16) * LDA + quad * 8];
        #pragma unroll
        for (int g = 0; g < CG; g++) {
            v8h b = *(const v8h*)&Bs[(g * 16 + l16) * LDA + quad * 8];
            acc[g] = __builtin_amdgcn_mfma_f32_16x16x32_f16(a, b, acc[g], 0, 0, 0);
        }
        __syncthreads();
    }
    #pragma unroll
    for (int reg = 0; reg < 4; reg++) {
        int row = row0 + wid * 16 + quad * 4 + reg;
        if (row < N) {
            float d = dis[row];
            #pragma unroll
            for (int g = 0; g < CG; g++)
                out[(size_t)row * F + g * 16 + l16] = __float2half(d * acc[g][reg]);
        }
    }
}

// ---------------- aggregation: pre[n] = fp16( dis[n]*(hd[n] + sum_{src} hd[src]) + b ) ----------------
// One wave per node, 16 B/lane gathers, packed fp16 accumulation (v_pk_add_f16).
// Per-accumulator fp16 chains are ~deg/(SUBS*U) adds (2-4) -> rounding noise ~3e-4.

template<int F, int U>
__global__ __launch_bounds__(NT) void agg_kernel(const __half* __restrict__ hd, const int* __restrict__ csr,
                                                 const int* __restrict__ row_start,
                                                 const float* __restrict__ dis, const float* __restrict__ b,
                                                 __half* __restrict__ pre, int N) {
    constexpr int LR = F / 8;      // lanes per row (16 B each)
    constexpr int SUBS = 64 / LR;  // rows gathered per wave-iteration
    constexpr int FSH = (F == 128) ? 7 : (F == 64) ? 6 : 5;
    int node = (blockIdx.x * NT + threadIdx.x) >> 6;
    int lane = threadIdx.x & 63;
    int fl = lane % LR, sub = lane / LR;
    if (node >= N) return;
    int beg = row_start[node];
    int cnt = row_start[node + 1] - beg;
    int fo = fl * 8;

    __half2 hacc[U][4];
    #pragma unroll
    for (int u = 0; u < U; u++)
        #pragma unroll
        for (int j = 0; j < 4; j++) hacc[u][j] = __halves2half2(__half(0.f), __half(0.f));

    int i = 0;
    for (; i + SUBS * U <= cnt; i += SUBS * U) {
        int s[U];
        #pragma unroll
        for (int u = 0; u < U; u++) s[u] = csr[beg + i + u * SUBS + sub];
        #pragma unroll
        for (int u = 0; u < U; u++) {
            int4 v = *(const int4*)(hd + ((s[u] << FSH) + fo));
            const __half2* hv = (const __half2*)&v;
            #pragma unroll
            for (int j = 0; j < 4; j++) hacc[u][j] = hacc[u][j] + hv[j];
        }
    }
    for (; i + sub < cnt; i += SUBS) {
        int s = csr[beg + i + sub];
        int4 v = *(const int4*)(hd + ((s << FSH) + fo));
        const __half2* hv = (const __half2*)&v;
        #pragma unroll
        for (int j = 0; j < 4; j++) hacc[0][j] = hacc[0][j] + hv[j];
    }
    if (sub == 0) {
        int4 v = *(const int4*)(hd + ((node << FSH) + fo));
        const __half2* hv = (const __half2*)&v;
        #pragma unroll
        for (int j = 0; j < 4; j++) hacc[0][j] = hacc[0][j] + hv[j];
    }
    // convert to f32 once, then exact cross-sub reduction
    float acc[8];
    #pragma unroll
    for (int j = 0; j < 4; j++) {
        float2 f = __half22float2(hacc[0][j]);
        acc[2 * j] = f.x; acc[2 * j + 1] = f.y;
    }
    #pragma unroll
    for (int u = 1; u < U; u++)
        #pragma unroll
        for (int j = 0; j < 4; j++) {
            float2 f = __half22float2(hacc[u][j]);
            acc[2 * j] += f.x; acc[2 * j + 1] += f.y;
        }
    #pragma unroll
    for (int m = LR; m < 64; m <<= 1)
        #pragma unroll
        for (int j = 0; j < 8; j++) acc[j] += __shfl_xor(acc[j], m, 64);
    if (sub == 0) {
        float d = dis[node];
        float4 b0 = *(const float4*)(b + fo);
        float4 b1 = *(const float4*)(b + fo + 4);
        __half2 h[4];
        h[0] = __floats2half2_rn(d * acc[0] + b0.x, d * acc[1] + b0.y);
        h[1] = __floats2half2_rn(d * acc[2] + b0.z, d * acc[3] + b0.w);
        h[2] = __floats2half2_rn(d * acc[4] + b1.x, d * acc[5] + b1.y);
        h[3] = __floats2half2_rn(d * acc[6] + b1.z, d * acc[7] + b1.w);
        *(int4*)(pre + ((node << FSH) + fo)) = *(int4*)h;
    }
}

// ---------------- BN statistics ----------------

template<int F>
__global__ __launch_bounds__(NT) void stats_kernel(const __half* __restrict__ pre, float* __restrict__ S1,
                                                   float* __restrict__ S2, int N) {
    constexpr int FP = F / 2;
    constexpr int RPB = NT / FP;
    int tid = threadIdx.x;
    int f = tid % FP, r0 = tid / FP;
    float s1x = 0.f, s1y = 0.f, s2x = 0.f, s2y = 0.f;
    const __half2* p2 = (const __half2*)pre;
    for (int node = blockIdx.x * RPB + r0; node < N; node += gridDim.x * RPB) {
        float2 v = __half22float2(p2[(size_t)node * FP + f]);
        s1x += v.x; s1y += v.y; s2x += v.x * v.x; s2y += v.y * v.y;
    }
    __shared__ float l1x[NT], l1y[NT], l2x[NT], l2y[NT];
    l1x[tid] = s1x; l1y[tid] = s1y; l2x[tid] = s2x; l2y[tid] = s2y;
    __syncthreads();
    if (tid < FP) {
        #pragma unroll
        for (int j = 1; j < RPB; j++) {
            s1x += l1x[tid + j * FP]; s1y += l1y[tid + j * FP];
            s2x += l2x[tid + j * FP]; s2y += l2y[tid + j * FP];
        }
        atomicAdd(&S1[2 * tid], s1x); atomicAdd(&S1[2 * tid + 1], s1y);
        atomicAdd(&S2[2 * tid], s2x); atomicAdd(&S2[2 * tid + 1], s2y);
    }
}

__global__ void params_kernel(const float* __restrict__ S1, const float* __restrict__ S2,
                              const float* __restrict__ g, const float* __restrict__ bt,
                              float* __restrict__ a, float* __restrict__ c, int N, int F) {
    int f = threadIdx.x;
    if (f < F) {
        float inv = 1.0f / (float)N;
        float mu = S1[f] * inv;
        float var = fmaxf(S2[f] * inv - mu * mu, 0.f);
        float av = g[f] * rsqrtf(var + EPS);
        a[f] = av;
        c[f] = bt[f] - mu * av;
    }
}

// ---------------- final FC: out[n] = relu(bn3(pre3[n])) @ Wfc + bfc ----------------

__global__ __launch_bounds__(NT) void fc_kernel(const __half* __restrict__ pre, const float* __restrict__ a,
                                                const float* __restrict__ c, const float* __restrict__ wfc,
                                                const float* __restrict__ bfc, float* __restrict__ out, int N) {
    __shared__ float wa[32], wc[32], ww[32];
    int tid = threadIdx.x;
    if (tid < 32) { wa[tid] = a[tid]; wc[tid] = c[tid]; ww[tid] = wfc[tid]; }
    __syncthreads();
    int n = blockIdx.x * NT + tid;
    if (n >= N) return;
    const __half2* p = (const __half2*)(pre + (size_t)n * 32);
    float acc = bfc[0];
    #pragma unroll
    for (int i = 0; i < 16; i++) {
        float2 v = __half22float2(p[i]);
        int f = i * 2;
        acc += fmaxf(v.x * wa[f] + wc[f], 0.f) * ww[f];
        acc += fmaxf(v.y * wa[f + 1] + wc[f + 1], 0.f) * ww[f + 1];
    }
    out[n] = acc;
}

// ---------------- launch ----------------

extern "C" void kernel_launch(void* const* d_in, const int* in_sizes, int n_in,
                              void* d_out, int out_size, void* d_ws, size_t ws_size,
                              hipStream_t stream) {
    const float* x   = (const float*)d_in[0];
    const int*   ei  = (const int*)d_in[1];
    const float* W1  = (const float*)d_in[2];
    const float* b1  = (const float*)d_in[3];
    const float* g1  = (const float*)d_in[4];
    const float* bt1 = (const float*)d_in[5];
    const float* W2  = (const float*)d_in[6];
    const float* b2  = (const float*)d_in[7];
    const float* g2  = (const float*)d_in[8];
    const float* bt2 = (const float*)d_in[9];
    const float* W3  = (const float*)d_in[10];
    const float* b3  = (const float*)d_in[11];
    const float* g3  = (const float*)d_in[12];
    const float* bt3 = (const float*)d_in[13];
    const float* Wfc = (const float*)d_in[14];
    const float* bfc = (const float*)d_in[15];
    float* out = (float*)d_out;

    int N = in_sizes[0] / 256;
    int E = in_sizes[1] / 2;
    const int* src = ei;
    const int* dst = ei + E;
    int NBUK = (N + BNODES - 1) >> BSH;

    char* ws = (char*)d_ws;
    size_t off = 0;
    auto alloc = [&](size_t bytes) -> char* {
        char* p = ws + off;
        off += (bytes + 255) & ~(size_t)255;
        return p;
    };
    __half* bufA     = (__half*)alloc((size_t)N * 128 * 2);
    __half* bufB     = (__half*)alloc((size_t)N * 128 * 2);
    int*   ebuf      = (int*)alloc((size_t)E * 4);
    int*   csr       = (int*)alloc((size_t)E * 4);
    int*   row_start = (int*)alloc((size_t)(N + 1) * 4);
    float* dis       = (float*)alloc((size_t)N * 4);
    int*   gbhist    = (int*)alloc((size_t)NBUK * 4);
    int*   bbase     = (int*)alloc((size_t)(NBUK + 1) * 4);
    int*   gcur      = (int*)alloc((size_t)NBUK * 4);
    __half* Wt1      = (__half*)alloc(256 * 128 * 2);
    __half* Wt2      = (__half*)alloc(128 * 64 * 2);
    __half* Wt3      = (__half*)alloc(64 * 32 * 2);
    float* stats = (float*)alloc(448 * 4 * 2);
    float* S1_1 = stats;       float* S2_1 = S1_1 + 128;
    float* S1_2 = S2_1 + 128;  float* S2_2 = S1_2 + 64;
    float* S1_3 = S2_2 + 64;   float* S2_3 = S1_3 + 32;
    float* a1 = S2_3 + 32; float* c1 = a1 + 128;
    float* a2 = c1 + 128;  float* c2 = a2 + 64;
    float* a3 = c2 + 64;   float* c3 = a3 + 32;

    hipMemsetAsync(gbhist, 0, (size_t)NBUK * 4, stream);
    hipMemsetAsync(stats, 0, 448 * 4, stream);

    // CSR build: bucket histogram -> scan -> partition -> per-bucket fill
    bhist_kernel<<<512, NT, 0, stream>>>(dst, gbhist, E, NBUK);
    bscan_kernel<<<1, NT, 0, stream>>>(gbhist, bbase, gcur, E, NBUK);
    part_kernel<<<(E + CH - 1) / CH, NT, 0, stream>>>(src, dst, gcur, ebuf, E, NBUK);
    bfill_kernel<<<NBUK, NT, 0, stream>>>(ebuf, bbase, row_start, dis, csr, N);
    prepw_kernel<<<(256 * 128 + 128 * 64 + 64 * 32 + NT - 1) / NT, NT, 0, stream>>>(W1, W2, W3, Wt1, Wt2, Wt3);

    int GB = (N + 63) / 64;
    int AB = (N + 3) / 4;   // one wave per node, 4 nodes per block
    int NB = (N + NT - 1) / NT;
    // layer 1
    mgemm_kernel<256, 128, false><<<GB, NT, 0, stream>>>(x, Wt1, dis, nullptr, nullptr, bufA, N);
    agg_kernel<128, 4><<<AB, NT, 0, stream>>>(bufA, csr, row_start, dis, b1, bufB, N);
    stats_kernel<128><<<256, NT, 0, stream>>>(bufB, S1_1, S2_1, N);
    params_kernel<<<1, 128, 0, stream>>>(S1_1, S2_1, g1, bt1, a1, c1, N, 128);
    // layer 2
    mgemm_kernel<128, 64, true><<<GB, NT, 0, stream>>>(bufB, Wt2, dis, a1, c1, bufA, N);
    agg_kernel<64, 2><<<AB, NT, 0, stream>>>(bufA, csr, row_start, dis, b2, bufB, N);
    stats_kernel<64><<<256, NT, 0, stream>>>(bufB, S1_2, S2_2, N);
    params_kernel<<<1, 64, 0, stream>>>(S1_2, S2_2, g2, bt2, a2, c2, N, 64);
    // layer 3
    mgemm_kernel<64, 32, true><<<GB, NT, 0, stream>>>(bufB, Wt3, dis, a2, c2, bufA, N);
    agg_kernel<32, 1><<<AB, NT, 0, stream>>>(bufA, csr, row_start, dis, b3, bufB, N);
    stats_kernel<32><<<256, NT, 0, stream>>>(bufB, S1_3, S2_3, N);
    params_kernel<<<1, 32, 0, stream>>>(S1_3, S2_3, g3, bt3, a3, c3, N, 32);
    // head
    fc_kernel<<<NB, NT, 0, stream>>>(bufB, a3, c3, Wfc, bfc, out, N);
}

// Round 8
// 604.313 us; speedup vs baseline: 2.1758x; 1.0312x over previous
//
#include <hip/hip_runtime.h>
#include <hip/hip_fp16.h>

#define EPS 1e-5f
constexpr int NT = 256;
constexpr int BSH = 9;            // bucket = dst >> 9 (512 nodes per bucket)
constexpr int BNODES = 1 << BSH;
constexpr int CH = 4096;          // edges per partition block
constexpr int PADCAP = 15 * BNODES; // extra per-bucket csr capacity for pad-to-16

typedef _Float16 v8h __attribute__((ext_vector_type(8)));
typedef float v4f __attribute__((ext_vector_type(4)));

// ---------------- bucket histogram (LDS-staged) ----------------

__global__ __launch_bounds__(NT) void bhist_kernel(const int* __restrict__ dst, int* __restrict__ gbhist,
                                                   int E, int NBUK) {
    __shared__ int h[512];
    int tid = threadIdx.x;
    for (int i = tid; i < 512; i += NT) h[i] = 0;
    __syncthreads();
    for (int e = blockIdx.x * NT + tid; e < E; e += gridDim.x * NT)
        atomicAdd(&h[dst[e] >> BSH], 1);
    __syncthreads();
    for (int i = tid; i < NBUK; i += NT)
        if (h[i]) atomicAdd(&gbhist[i], h[i]);
}

// ---------------- bucket scan: bbase[0..NBUK] (exclusive), gcur = bbase ----------------

__global__ __launch_bounds__(NT) void bscan_kernel(const int* __restrict__ gbhist, int* __restrict__ bbase,
                                                   int* __restrict__ gcur, int E, int NBUK) {
    __shared__ int wsum[5];
    int tid = threadIdx.x;
    int lane = tid & 63, wid = tid >> 6;
    int e0 = (2 * tid < NBUK) ? gbhist[2 * tid] : 0;
    int e1 = (2 * tid + 1 < NBUK) ? gbhist[2 * tid + 1] : 0;
    int u = e0 + e1;
    int incl = u;
    #pragma unroll
    for (int off = 1; off < 64; off <<= 1) {
        int t = __shfl_up(incl, off, 64);
        if (lane >= off) incl += t;
    }
    if (lane == 63) wsum[wid] = incl;
    __syncthreads();
    if (tid == 0) { int s = 0; for (int w = 0; w < 4; w++) { int t = wsum[w]; wsum[w] = s; s += t; } }
    __syncthreads();
    int base = wsum[wid] + incl - u;
    if (2 * tid < NBUK)     { bbase[2 * tid] = base;          gcur[2 * tid] = base; }
    if (2 * tid + 1 < NBUK) { bbase[2 * tid + 1] = base + e0; gcur[2 * tid + 1] = base + e0; }
    if (tid == 0) bbase[NBUK] = E;
}

// ---------------- phase 1 body: partition edges into ebuf by bucket ----------------
// ebuf entry: (dst & 511) << 18 | src   (N < 2^18)

__device__ __forceinline__ void part_body(int bx, const int* __restrict__ src, const int* __restrict__ dst,
                                          int* __restrict__ gcur, int* __restrict__ ebuf,
                                          int E, int NBUK, char* smem) {
    constexpr int EPT = CH / NT;   // 16 edges per thread
    int* hist  = (int*)smem;             // 512
    int* lscan = hist + 512;             // 512
    int* gbase = lscan + 512;            // 512
    int2* stage = (int2*)(gbase + 512);  // CH int2 = 32 KB
    int tid = threadIdx.x;
    int lane = tid & 63;
    int e0 = bx * CH;

    for (int i = tid; i < 512; i += NT) hist[i] = 0;
    __syncthreads();

    int2 ed[EPT]; int rank[EPT]; int buk[EPT];
    #pragma unroll
    for (int j = 0; j < EPT; j++) {
        int e = e0 + j * NT + tid;
        if (e < E) {
            ed[j].x = src[e]; ed[j].y = dst[e];
            buk[j] = ed[j].y >> BSH;
            rank[j] = atomicAdd(&hist[buk[j]], 1);
        } else buk[j] = -1;
    }
    __syncthreads();
    if (tid < 64) {
        int bi = tid * 8;
        int v[8]; int s = 0;
        #pragma unroll
        for (int j = 0; j < 8; j++) { v[j] = s; s += hist[bi + j]; }
        int incl = s;
        #pragma unroll
        for (int off = 1; off < 64; off <<= 1) {
            int t = __shfl_up(incl, off, 64);
            if (lane >= off) incl += t;
        }
        int lb = incl - s;
        #pragma unroll
        for (int j = 0; j < 8; j++) lscan[bi + j] = lb + v[j];
    }
    __syncthreads();
    for (int i = tid; i < NBUK; i += NT) {
        int c = hist[i];
        gbase[i] = c ? atomicAdd(&gcur[i], c) : 0;
    }
    #pragma unroll
    for (int j = 0; j < EPT; j++)
        if (buk[j] >= 0) stage[lscan[buk[j]] + rank[j]] = ed[j];
    __syncthreads();
    int cnt = min(E - e0, CH);
    for (int i = tid; i < cnt; i += NT) {
        int2 e = stage[i];
        int b = e.y >> BSH;
        ebuf[gbase[b] + (i - lscan[b])] = ((e.y & (BNODES - 1)) << 18) | e.x;
    }
}

// ---------------- phase 2 body: per-bucket row_start/pdeg/dis + padded csr fill ----------------
// csr rows padded to multiple of 16 with sentinel node N (hd row N is zero in EVERY layout:
// mgemm epilogue writes zeros at row N).

__device__ __forceinline__ void bfill_body(int bx, const int* __restrict__ ebuf, const int* __restrict__ bbase,
                                           int* __restrict__ row_start, int* __restrict__ pdeg,
                                           float* __restrict__ dis, __half* __restrict__ dis_h,
                                           int* __restrict__ csr, int N, char* smem) {
    int* ldeg = (int*)smem;      // 512
    int* lrs  = ldeg + 512;      // 512
    int* wsum = lrs + 512;       // 8
    int tid = threadIdx.x;
    int lane = tid & 63, wid = tid >> 6;
    int b = bx;
    int node0 = b << BSH;
    int nn = min(BNODES, N - node0);
    int beg = bbase[b], end = bbase[b + 1];
    int begp = beg + b * PADCAP;

    for (int i = tid; i < BNODES; i += NT) ldeg[i] = 0;
    __syncthreads();
    for (int i = beg + tid; i < end; i += NT)
        atomicAdd(&ldeg[ebuf[i] >> 18], 1);
    __syncthreads();
    int e0 = ldeg[2 * tid], e1 = ldeg[2 * tid + 1];
    int p0 = (e0 + 15) & ~15, p1 = (e1 + 15) & ~15;
    int u = p0 + p1;
    int incl = u;
    #pragma unroll
    for (int off = 1; off < 64; off <<= 1) {
        int t = __shfl_up(incl, off, 64);
        if (lane >= off) incl += t;
    }
    if (lane == 63) wsum[wid] = incl;
    __syncthreads();
    if (tid == 0) { int s = 0; for (int w = 0; w < 4; w++) { int t = wsum[w]; wsum[w] = s; s += t; } }
    __syncthreads();
    int base = wsum[wid] + incl - u;
    lrs[2 * tid] = base;
    lrs[2 * tid + 1] = base + p0;
    __syncthreads();
    for (int i = tid; i < nn; i += NT) {
        int dg = ldeg[i];
        pdeg[node0 + i] = (dg + 15) & ~15;
        row_start[node0 + i] = begp + lrs[i];
        float dv = rsqrtf((float)dg + 1.0f);
        dis[node0 + i] = dv;
        dis_h[node0 + i] = __float2half(dv);
    }
    if (bx == 0 && tid == 0) dis_h[N] = __float2half(0.f);
    __syncthreads();
    for (int i = tid; i < BNODES; i += NT) ldeg[i] = 0;   // reuse as cursor
    __syncthreads();
    for (int i = beg + tid; i < end; i += NT) {
        int code = ebuf[i];
        int l = code >> 18;
        int off = atomicAdd(&ldeg[l], 1);
        csr[begp + lrs[l] + off] = code & 0x3FFFF;
    }
    __syncthreads();
    // pad fill: sentinel N (zero row)
    for (int i = tid; i < nn; i += NT) {
        int dg = ldeg[i];
        int pd = (dg + 15) & ~15;
        int cbase = begp + lrs[i];
        for (int k = dg; k < pd; k++) csr[cbase + k] = N;
    }
}

// ---------------- weight prep + zero sentinel row of bufA (128-layout; belt & braces) ----------------

__global__ __launch_bounds__(NT) void prepw_kernel(const float* __restrict__ W1, const float* __restrict__ W2,
                                                   const float* __restrict__ W3, __half* __restrict__ Wt1,
                                                   __half* __restrict__ Wt2, __half* __restrict__ Wt3,
                                                   __half* __restrict__ bufA, int N) {
    int i = blockIdx.x * NT + threadIdx.x;
    if (i < 256 * 128) {
        int k = i >> 7, f = i & 127;
        Wt1[f * 256 + k] = __float2half(W1[i]);
    } else if (i < 256 * 128 + 128 * 64) {
        int j = i - 256 * 128; int k = j >> 6, f = j & 63;
        Wt2[f * 128 + k] = __float2half(W2[j]);
    } else if (i < 256 * 128 + 128 * 64 + 64 * 32) {
        int j = i - 256 * 128 - 128 * 64; int k = j >> 5, f = j & 31;
        Wt3[f * 64 + k] = __float2half(W3[j]);
    } else if (i < 256 * 128 + 128 * 64 + 64 * 32 + 128) {
        bufA[(size_t)N * 128 + (i - (256 * 128 + 128 * 64 + 64 * 32))] = __float2half(0.f);
    }
}

// ---------------- MFMA GEMM body ----------------
// NORM: computes BN affine from S1/S2/g/bt inline, applies relu(v*a+c) on fp16 load.
// SC:   scales output row by dis[row].
// Epilogue ALSO writes zeros at row N (sentinel row for padded agg; acc there is exactly 0
// because A-staging zero-pads rows >= N).

template<int K, int F, bool NORM, bool SC>
__device__ __forceinline__ void mgemm_body(int bx, const void* __restrict__ Xv, const __half* __restrict__ Wt,
                                           const float* __restrict__ dis, const float* __restrict__ S1,
                                           const float* __restrict__ S2, const float* __restrict__ g,
                                           const float* __restrict__ bt, __half* __restrict__ out, int N,
                                           char* smem) {
    constexpr int KC = 32;
    constexpr int CG = F / 16;
    constexpr int LDA = KC + 8;
    __half* As = (__half*)smem;                      // 64*LDA
    __half* Bs = (__half*)(smem + 64 * LDA * 2);     // F*LDA
    float* as_ = (float*)(smem + 64 * LDA * 2 + F * LDA * 2);
    float* cs_ = as_ + K;

    int tid = threadIdx.x;
    if constexpr (NORM) {
        float inv = 1.0f / (float)N;
        for (int i = tid; i < K; i += NT) {
            float mu = S1[i] * inv;
            float var = fmaxf(S2[i] * inv - mu * mu, 0.f);
            float av = g[i] * rsqrtf(var + EPS);
            as_[i] = av;
            cs_[i] = bt[i] - mu * av;
        }
        __syncthreads();
    }
    int row0 = bx * 64;
    int wid = tid >> 6, lane = tid & 63;
    int quad = lane >> 4, l16 = lane & 15;
    int tr = tid >> 3;
    int tk = (tid & 7) * 4;

    v4f acc[CG];
    #pragma unroll
    for (int gg = 0; gg < CG; gg++) acc[gg] = (v4f)0.f;

    for (int k0 = 0; k0 < K; k0 += KC) {
        #pragma unroll
        for (int r = tr; r < 64; r += 32) {
            int row = row0 + r;
            __half h0, h1, h2, h3;
            if (row < N) {
                if constexpr (NORM) {
                    const __half2* xp = (const __half2*)((const __half*)Xv + (size_t)row * K + k0 + tk);
                    float2 v0 = __half22float2(xp[0]);
                    float2 v1 = __half22float2(xp[1]);
                    h0 = __float2half(fmaxf(v0.x * as_[k0 + tk]     + cs_[k0 + tk],     0.f));
                    h1 = __float2half(fmaxf(v0.y * as_[k0 + tk + 1] + cs_[k0 + tk + 1], 0.f));
                    h2 = __float2half(fmaxf(v1.x * as_[k0 + tk + 2] + cs_[k0 + tk + 2], 0.f));
                    h3 = __float2half(fmaxf(v1.y * as_[k0 + tk + 3] + cs_[k0 + tk + 3], 0.f));
                } else {
                    float4 v = *(const float4*)((const float*)Xv + (size_t)row * K + k0 + tk);
                    h0 = __float2half(v.x); h1 = __float2half(v.y);
                    h2 = __float2half(v.z); h3 = __float2half(v.w);
                }
            } else {
                h0 = h1 = h2 = h3 = __float2half(0.f);
            }
            __half2* dst = (__half2*)&As[r * LDA + tk];
            dst[0] = __halves2half2(h0, h1);
            dst[1] = __halves2half2(h2, h3);
        }
        #pragma unroll
        for (int n = tr; n < F; n += 32) {
            const __half2* wp = (const __half2*)(Wt + (size_t)n * K + k0 + tk);
            __half2* dst = (__half2*)&Bs[n * LDA + tk];
            dst[0] = wp[0];
            dst[1] = wp[1];
        }
        __syncthreads();
        v8h a = *(const v8h*)&As[(wid * 16 + l16) * LDA + quad * 8];
        #pragma unroll
        for (int gg = 0; gg < CG; gg++) {
            v8h b = *(const v8h*)&Bs[(gg * 16 + l16) * LDA + quad * 8];
            acc[gg] = __builtin_amdgcn_mfma_f32_16x16x32_f16(a, b, acc[gg], 0, 0, 0);
        }
        __syncthreads();
    }
    #pragma unroll
    for (int reg = 0; reg < 4; reg++) {
        int row = row0 + wid * 16 + quad * 4 + reg;
        if (row < N) {
            float d = SC ? dis[row] : 1.0f;
            #pragma unroll
            for (int gg = 0; gg < CG; gg++)
                out[(size_t)row * F + gg * 16 + l16] = __float2half(d * acc[gg][reg]);
        } else if (row == N) {
            // sentinel row for padded agg: acc is exactly 0 here (A zero-padded)
            #pragma unroll
            for (int gg = 0; gg < CG; gg++)
                out[(size_t)row * F + gg * 16 + l16] = __float2half(0.f);
        }
    }
}

template<int K, int F, bool NORM, bool SC>
__global__ __launch_bounds__(NT) void mgemm_kernel(const void* __restrict__ Xv, const __half* __restrict__ Wt,
                                                   const float* __restrict__ dis, const float* __restrict__ S1,
                                                   const float* __restrict__ S2, const float* __restrict__ g,
                                                   const float* __restrict__ bt, __half* __restrict__ out, int N) {
    constexpr int SMB = 64 * 40 * 2 + F * 40 * 2 + (NORM ? 8 * K : 0);
    __shared__ __align__(16) char smem[SMB];
    mgemm_body<K, F, NORM, SC>(blockIdx.x, Xv, Wt, dis, S1, S2, g, bt, out, N, smem);
}

// ---------------- fat kernels: CSR build || gemm1 (gemm1 needs no dis now) ----------------

__global__ __launch_bounds__(NT) void fat1_kernel(const int* __restrict__ src, const int* __restrict__ dst,
                                                  int* __restrict__ gcur, int* __restrict__ ebuf, int E, int NBUK,
                                                  int PB, const float* __restrict__ x, const __half* __restrict__ Wt1,
                                                  __half* __restrict__ bufA, int N) {
    __shared__ __align__(16) char smem[38912];
    if ((int)blockIdx.x < PB)
        part_body(blockIdx.x, src, dst, gcur, ebuf, E, NBUK, smem);
    else
        mgemm_body<256, 128, false, false>((int)blockIdx.x - PB, x, Wt1, nullptr, nullptr, nullptr, nullptr,
                                           nullptr, bufA, N, smem);
}

__global__ __launch_bounds__(NT) void fat2_kernel(const int* __restrict__ ebuf, const int* __restrict__ bbase,
                                                  int* __restrict__ row_start, int* __restrict__ pdeg,
                                                  float* __restrict__ dis, __half* __restrict__ dis_h,
                                                  int* __restrict__ csr, const float* __restrict__ x,
                                                  const __half* __restrict__ Wt1, __half* __restrict__ bufA,
                                                  int N, int NBUK, int A) {
    __shared__ __align__(16) char smem[15872];
    if ((int)blockIdx.x < NBUK)
        bfill_body(blockIdx.x, ebuf, bbase, row_start, pdeg, dis, dis_h, csr, N, smem);
    else
        mgemm_body<256, 128, false, false>((int)blockIdx.x - NBUK + A, x, Wt1, nullptr, nullptr, nullptr, nullptr,
                                           nullptr, bufA, N, smem);
}

// ---------------- aggregation: pre[n] = fp16( dis[n]*(Σ terms) + b ) ----------------
// Branch-free padded loop (pdeg multiple of 16, pads point to zero row N).
// DISW: per-edge v_pk_fma with dis_h[src] (layer 1, hd unscaled); else v_pk_add (hd pre-scaled).

template<int F, int U, bool DISW>
__global__ __launch_bounds__(NT) void agg_kernel(const __half* __restrict__ hd, const int* __restrict__ csr,
                                                 const int* __restrict__ row_start, const int* __restrict__ pdeg,
                                                 const __half* __restrict__ dis_h, const float* __restrict__ dis,
                                                 const float* __restrict__ b, __half* __restrict__ pre, int N) {
    constexpr int LR = F / 8;      // lanes per row (16 B each)
    constexpr int SUBS = 64 / LR;  // rows gathered per wave-iteration; SUBS*U == 16
    constexpr int FSH = (F == 128) ? 7 : (F == 64) ? 6 : 5;
    int node = (blockIdx.x * NT + threadIdx.x) >> 6;
    if (node >= N) return;
    int lane = threadIdx.x & 63;
    int fl = lane % LR, sub = lane / LR;
    int beg = row_start[node];
    int iters = pdeg[node] >> 4;
    int fo = fl * 8;

    __half2 hacc[U][4];
    #pragma unroll
    for (int u = 0; u < U; u++)
        #pragma unroll
        for (int j = 0; j < 4; j++) hacc[u][j] = __half2half2(__half(0.f));

    if (sub == 0) {   // self term
        int4 v = *(const int4*)(hd + (((size_t)node << FSH) + fo));
        const __half2* hv = (const __half2*)&v;
        if constexpr (DISW) {
            __half2 dd = __half2half2(dis_h[node]);
            #pragma unroll
            for (int j = 0; j < 4; j++) hacc[0][j] = __hmul2(hv[j], dd);
        } else {
            #pragma unroll
            for (int j = 0; j < 4; j++) hacc[0][j] = hv[j];
        }
    }
    const int* cp = csr + beg + sub;
    for (int it = 0; it < iters; ++it) {
        int s[U];
        #pragma unroll
        for (int u = 0; u < U; u++) s[u] = cp[u * SUBS];
        cp += 16;
        #pragma unroll
        for (int u = 0; u < U; u++) {
            int4 v = *(const int4*)(hd + (((size_t)s[u] << FSH) + fo));
            const __half2* hv = (const __half2*)&v;
            if constexpr (DISW) {
                __half2 dd = __half2half2(dis_h[s[u]]);
                #pragma unroll
                for (int j = 0; j < 4; j++) hacc[u][j] = __hfma2(hv[j], dd, hacc[u][j]);
            } else {
                #pragma unroll
                for (int j = 0; j < 4; j++) hacc[u][j] = __hadd2(hacc[u][j], hv[j]);
            }
        }
    }
    // convert to f32 once, then exact cross-sub reduction
    float acc[8];
    #pragma unroll
    for (int j = 0; j < 4; j++) {
        float2 f = __half22float2(hacc[0][j]);
        acc[2 * j] = f.x; acc[2 * j + 1] = f.y;
    }
    #pragma unroll
    for (int u = 1; u < U; u++)
        #pragma unroll
        for (int j = 0; j < 4; j++) {
            float2 f = __half22float2(hacc[u][j]);
            acc[2 * j] += f.x; acc[2 * j + 1] += f.y;
        }
    #pragma unroll
    for (int m = LR; m < 64; m <<= 1)
        #pragma unroll
        for (int j = 0; j < 8; j++) acc[j] += __shfl_xor(acc[j], m, 64);
    if (sub == 0) {
        float d = dis[node];
        float4 b0 = *(const float4*)(b + fo);
        float4 b1 = *(const float4*)(b + fo + 4);
        __half2 h[4];
        h[0] = __floats2half2_rn(d * acc[0] + b0.x, d * acc[1] + b0.y);
        h[1] = __floats2half2_rn(d * acc[2] + b0.z, d * acc[3] + b0.w);
        h[2] = __floats2half2_rn(d * acc[4] + b1.x, d * acc[5] + b1.y);
        h[3] = __floats2half2_rn(d * acc[6] + b1.z, d * acc[7] + b1.w);
        *(int4*)(pre + (((size_t)node << FSH) + fo)) = *(int4*)h;
    }
}

// ---------------- BN statistics ----------------

template<int F>
__global__ __launch_bounds__(NT) void stats_kernel(const __half* __restrict__ pre, float* __restrict__ S1,
                                                   float* __restrict__ S2, int N) {
    constexpr int FP = F / 2;
    constexpr int RPB = NT / FP;
    int tid = threadIdx.x;
    int f = tid % FP, r0 = tid / FP;
    float s1x = 0.f, s1y = 0.f, s2x = 0.f, s2y = 0.f;
    const __half2* p2 = (const __half2*)pre;
    for (int node = blockIdx.x * RPB + r0; node < N; node += gridDim.x * RPB) {
        float2 v = __half22float2(p2[(size_t)node * FP + f]);
        s1x += v.x; s1y += v.y; s2x += v.x * v.x; s2y += v.y * v.y;
    }
    __shared__ float l1x[NT], l1y[NT], l2x[NT], l2y[NT];
    l1x[tid] = s1x; l1y[tid] = s1y; l2x[tid] = s2x; l2y[tid] = s2y;
    __syncthreads();
    if (tid < FP) {
        #pragma unroll
        for (int j = 1; j < RPB; j++) {
            s1x += l1x[tid + j * FP]; s1y += l1y[tid + j * FP];
            s2x += l2x[tid + j * FP]; s2y += l2y[tid + j * FP];
        }
        atomicAdd(&S1[2 * tid], s1x); atomicAdd(&S1[2 * tid + 1], s1y);
        atomicAdd(&S2[2 * tid], s2x); atomicAdd(&S2[2 * tid + 1], s2y);
    }
}

// ---------------- final FC (BN3 params computed inline) ----------------

__global__ __launch_bounds__(NT) void fc_kernel(const __half* __restrict__ pre, const float* __restrict__ S1,
                                                const float* __restrict__ S2, const float* __restrict__ g,
                                                const float* __restrict__ bt, const float* __restrict__ wfc,
                                                const float* __restrict__ bfc, float* __restrict__ out, int N) {
    __shared__ float wa[32], wc[32], ww[32];
    int tid = threadIdx.x;
    if (tid < 32) {
        float inv = 1.0f / (float)N;
        float mu = S1[tid] * inv;
        float var = fmaxf(S2[tid] * inv - mu * mu, 0.f);
        float av = g[tid] * rsqrtf(var + EPS);
        wa[tid] = av; wc[tid] = bt[tid] - mu * av; ww[tid] = wfc[tid];
    }
    __syncthreads();
    int n = blockIdx.x * NT + tid;
    if (n >= N) return;
    const __half2* p = (const __half2*)(pre + (size_t)n * 32);
    float acc = bfc[0];
    #pragma unroll
    for (int i = 0; i < 16; i++) {
        float2 v = __half22float2(p[i]);
        int f = i * 2;
        acc += fmaxf(v.x * wa[f] + wc[f], 0.f) * ww[f];
        acc += fmaxf(v.y * wa[f + 1] + wc[f + 1], 0.f) * ww[f + 1];
    }
    out[n] = acc;
}

// ---------------- launch ----------------

extern "C" void kernel_launch(void* const* d_in, const int* in_sizes, int n_in,
                              void* d_out, int out_size, void* d_ws, size_t ws_size,
                              hipStream_t stream) {
    const float* x   = (const float*)d_in[0];
    const int*   ei  = (const int*)d_in[1];
    const float* W1  = (const float*)d_in[2];
    const float* b1  = (const float*)d_in[3];
    const float* g1  = (const float*)d_in[4];
    const float* bt1 = (const float*)d_in[5];
    const float* W2  = (const float*)d_in[6];
    const float* b2  = (const float*)d_in[7];
    const float* g2  = (const float*)d_in[8];
    const float* bt2 = (const float*)d_in[9];
    const float* W3  = (const float*)d_in[10];
    const float* b3  = (const float*)d_in[11];
    const float* g3  = (const float*)d_in[12];
    const float* bt3 = (const float*)d_in[13];
    const float* Wfc = (const float*)d_in[14];
    const float* bfc = (const float*)d_in[15];
    float* out = (float*)d_out;

    int N = in_sizes[0] / 256;
    int E = in_sizes[1] / 2;
    const int* src = ei;
    const int* dst = ei + E;
    int NBUK = (N + BNODES - 1) >> BSH;

    char* ws = (char*)d_ws;
    size_t off = 0;
    auto alloc = [&](size_t bytes) -> char* {
        char* p = ws + off;
        off += (bytes + 255) & ~(size_t)255;
        return p;
    };
    __half* bufA     = (__half*)alloc((size_t)(N + 1) * 128 * 2);   // h / hd (row N = zero sentinel in all layouts)
    __half* bufB     = (__half*)alloc((size_t)N * 128 * 2);         // pre-BN aggregated
    int*   ebuf      = (int*)alloc((size_t)E * 4);
    int*   csr       = (int*)alloc(((size_t)E + (size_t)NBUK * PADCAP) * 4);
    int*   row_start = (int*)alloc((size_t)N * 4);
    int*   pdeg      = (int*)alloc((size_t)N * 4);
    float* dis       = (float*)alloc((size_t)N * 4);
    __half* dis_h    = (__half*)alloc((size_t)(N + 1) * 2);
    int*   gbhist    = (int*)alloc((size_t)NBUK * 4);
    int*   bbase     = (int*)alloc((size_t)(NBUK + 1) * 4);
    int*   gcur      = (int*)alloc((size_t)NBUK * 4);
    __half* Wt1      = (__half*)alloc(256 * 128 * 2);
    __half* Wt2      = (__half*)alloc(128 * 64 * 2);
    __half* Wt3      = (__half*)alloc(64 * 32 * 2);
    float* stats = (float*)alloc(448 * 4);
    float* S1_1 = stats;       float* S2_1 = S1_1 + 128;
    float* S1_2 = S2_1 + 128;  float* S2_2 = S1_2 + 64;
    float* S1_3 = S2_2 + 64;   float* S2_3 = S1_3 + 32;

    hipMemsetAsync(gbhist, 0, (size_t)NBUK * 4, stream);
    hipMemsetAsync(stats, 0, 448 * 4, stream);

    int GB = (N + 63) / 64;
    int PB = (E + CH - 1) / CH;
    int A = (GB * 3) / 5;           // gemm1 tiles in FAT1; rest in FAT2
    int AB = (N + 3) / 4;           // agg: one wave per node
    int NB = (N + NT - 1) / NT;

    prepw_kernel<<<(256 * 128 + 128 * 64 + 64 * 32 + 128 + NT - 1) / NT, NT, 0, stream>>>(
        W1, W2, W3, Wt1, Wt2, Wt3, bufA, N);
    bhist_kernel<<<512, NT, 0, stream>>>(dst, gbhist, E, NBUK);
    bscan_kernel<<<1, NT, 0, stream>>>(gbhist, bbase, gcur, E, NBUK);
    fat1_kernel<<<PB + A, NT, 0, stream>>>(src, dst, gcur, ebuf, E, NBUK, PB, x, Wt1, bufA, N);
    fat2_kernel<<<NBUK + (GB - A), NT, 0, stream>>>(ebuf, bbase, row_start, pdeg, dis, dis_h, csr,
                                                    x, Wt1, bufA, N, NBUK, A);
    // layer 1 (hd unscaled -> DISW agg)
    agg_kernel<128, 4, true><<<AB, NT, 0, stream>>>(bufA, csr, row_start, pdeg, dis_h, dis, b1, bufB, N);
    stats_kernel<128><<<256, NT, 0, stream>>>(bufB, S1_1, S2_1, N);
    // layer 2
    mgemm_kernel<128, 64, true, true><<<GB, NT, 0, stream>>>(bufB, Wt2, dis, S1_1, S2_1, g1, bt1, bufA, N);
    agg_kernel<64, 2, false><<<AB, NT, 0, stream>>>(bufA, csr, row_start, pdeg, dis_h, dis, b2, bufB, N);
    stats_kernel<64><<<256, NT, 0, stream>>>(bufB, S1_2, S2_2, N);
    // layer 3
    mgemm_kernel<64, 32, true, true><<<GB, NT, 0, stream>>>(bufB, Wt3, dis, S1_2, S2_2, g2, bt2, bufA, N);
    agg_kernel<32, 1, false><<<AB, NT, 0, stream>>>(bufA, csr, row_start, pdeg, dis_h, dis, b3, bufB, N);
    stats_kernel<32><<<256, NT, 0, stream>>>(bufB, S1_3, S2_3, N);
    // head
    fc_kernel<<<NB, NT, 0, stream>>>(bufB, S1_3, S2_3, g3, bt3, Wfc, bfc, out, N);
}